// Round 3
// baseline (5732.819 us; speedup 1.0000x reference)
//
#include <hip/hip_runtime.h>
#include <hip/hip_bf16.h>

#define IN_F 256
#define K_TOT 512
#define BM 32
#define BK 16

// Wt[k][j]: k<256 -> W_self[j][k], else W_neigh[j][k-256]  (512x256 f32)
__global__ void build_wt_kernel(const float* __restrict__ Ws,
                                const float* __restrict__ Wn,
                                float* __restrict__ Wt) {
  int idx = blockIdx.x * 256 + threadIdx.x;  // 0 .. 512*256-1
  int k = idx >> 8;
  int j = idx & 255;
  float v = (k < IN_F) ? Ws[j * IN_F + k] : Wn[j * IN_F + (k - IN_F)];
  Wt[idx] = v;
}

// Detect whether edge_index arrived as int64 (little-endian lo/hi pairs) or
// int32. For int64 values in [0, N), every odd 32-bit word is 0. For int32
// random row indices, P(odd word == 0) = 1e-5 each -> 2048 samples decisive.
__global__ void detect_i64_kernel(const int* __restrict__ ei, int* __restrict__ flag) {
  __shared__ int bad_s[256];
  int t = threadIdx.x;
  int bad = 0;
#pragma unroll
  for (int p = 0; p < 8; ++p) {
    int i = t + p * 256;                 // pair index 0..2047
    if (ei[2 * i + 1] != 0) bad = 1;
  }
  bad_s[t] = bad;
  __syncthreads();
  for (int s = 128; s > 0; s >>= 1) {
    if (t < s) bad_s[t] |= bad_s[t + s];
    __syncthreads();
  }
  if (t == 0) *flag = (bad_s[0] == 0) ? 1 : 0;  // 1 => int64 layout
}

// One wave per edge: gather x[src] (1KB coalesced), scale by w, scatter-add
// into num[dst] via f32 atomics. lane 0 accumulates wsum[dst].
__global__ void scatter_kernel(const float* __restrict__ x,
                               const int* __restrict__ ei,
                               const float* __restrict__ ew,
                               float* __restrict__ num,
                               float* __restrict__ wsum,
                               const int* __restrict__ flag,
                               int E) {
  long long gt = (long long)blockIdx.x * blockDim.x + threadIdx.x;
  int e = (int)(gt >> 6);
  if (e >= E) return;
  int lane = (int)(gt & 63);
  int is64 = *flag;  // uniform, L2-cached
  int src, dst;
  if (is64) {
    src = ei[2 * e];                         // lo word of int64 element e
    dst = ei[2 * (E + e)];                   // lo word of int64 element E+e
  } else {
    src = ei[e];
    dst = ei[E + e];
  }
  float wgt = ew[e];
  float4 v = reinterpret_cast<const float4*>(x + (size_t)src * IN_F)[lane];
  float* d = num + (size_t)dst * IN_F + lane * 4;
  atomicAdd(d + 0, v.x * wgt);
  atomicAdd(d + 1, v.y * wgt);
  atomicAdd(d + 2, v.z * wgt);
  atomicAdd(d + 3, v.w * wgt);
  if (lane == 0) atomicAdd(wsum + dst, wgt);
}

// C[32 rows x 256 cols] per block. 4 waves; wave w owns rows w*8..w*8+7,
// lane owns cols lane*4..lane*4+3 (acc 8x4). A staged transposed+scaled in
// LDS, B staged as a contiguous 16KB copy of Wt rows. Epilogue: bias add,
// full-wave shfl_xor sumsq reduce per row, rsqrt scale, float4 store.
__launch_bounds__(256)
__global__ void gemm_norm_kernel(const float* __restrict__ x,
                                 const float* __restrict__ num,
                                 const float* __restrict__ wsum,
                                 const float* __restrict__ Wt,
                                 const float* __restrict__ bias,
                                 float* __restrict__ out,
                                 int N) {
  const int t = threadIdx.x;
  const int lane = t & 63;
  const int w = t >> 6;
  const int row0 = blockIdx.x * BM;

  __shared__ float As[BK][BM + 4];
  __shared__ float Bs[BK * IN_F];
  __shared__ float invw_s[BM];

  if (t < BM) {
    int gr = row0 + t;
    float ws = (gr < N) ? wsum[gr] : 1.0f;
    invw_s[t] = 1.0f / fmaxf(ws, 1e-8f);
  }

  float acc[8][4];
#pragma unroll
  for (int r = 0; r < 8; ++r)
#pragma unroll
    for (int c = 0; c < 4; ++c) acc[r][c] = 0.0f;

  const float4* Wt4 = reinterpret_cast<const float4*>(Wt);
  float4* Bs4 = reinterpret_cast<float4*>(Bs);

  __syncthreads();

  for (int k0 = 0; k0 < K_TOT; k0 += BK) {
    // stage B: contiguous 16KB block of Wt -> coalesced global, linear LDS
#pragma unroll
    for (int p = 0; p < 4; ++p)
      Bs4[p * 256 + t] = Wt4[(k0 << 6) + p * 256 + t];
    // stage A transposed: As[kk][r] = A[row0+r][k0+kk] (neigh half scaled)
    {
      int r = t >> 3;
      int kk = (t & 7) << 1;
      int k = k0 + kk;
      int gr = row0 + r;
      int grc = (gr < N) ? gr : (N - 1);
      float a0, a1;
      if (k < IN_F) {
        const float2 v = *reinterpret_cast<const float2*>(x + (size_t)grc * IN_F + k);
        a0 = v.x;
        a1 = v.y;
      } else {
        const float2 v = *reinterpret_cast<const float2*>(num + (size_t)grc * IN_F + (k - IN_F));
        float m = invw_s[r];
        a0 = v.x * m;
        a1 = v.y * m;
      }
      As[kk][r] = a0;
      As[kk + 1][r] = a1;
    }
    __syncthreads();
#pragma unroll
    for (int kk = 0; kk < BK; ++kk) {
      float bf[4], af[8];
      *reinterpret_cast<float4*>(&bf[0]) =
          *reinterpret_cast<const float4*>(&Bs[kk * IN_F + lane * 4]);
      *reinterpret_cast<float4*>(&af[0]) =
          *reinterpret_cast<const float4*>(&As[kk][w * 8]);
      *reinterpret_cast<float4*>(&af[4]) =
          *reinterpret_cast<const float4*>(&As[kk][w * 8 + 4]);
#pragma unroll
      for (int r = 0; r < 8; ++r)
#pragma unroll
        for (int c = 0; c < 4; ++c) acc[r][c] += af[r] * bf[c];
    }
    __syncthreads();
  }

  float bf[4];
  *reinterpret_cast<float4*>(&bf[0]) = reinterpret_cast<const float4*>(bias)[lane];

#pragma unroll
  for (int r = 0; r < 8; ++r) {
    float ss = 0.0f;
#pragma unroll
    for (int c = 0; c < 4; ++c) {
      float v = acc[r][c] + bf[c];
      acc[r][c] = v;
      ss += v * v;
    }
#pragma unroll
    for (int s = 1; s < 64; s <<= 1) ss += __shfl_xor(ss, s, 64);
    int gr = row0 + w * 8 + r;
    if (gr < N) {
      float scale = 1.0f / fmaxf(sqrtf(ss), 1e-12f);
      float4 st;
      st.x = acc[r][0] * scale;
      st.y = acc[r][1] * scale;
      st.z = acc[r][2] * scale;
      st.w = acc[r][3] * scale;
      *reinterpret_cast<float4*>(out + (size_t)gr * IN_F + lane * 4) = st;
    }
  }
}

extern "C" void kernel_launch(void* const* d_in, const int* in_sizes, int n_in,
                              void* d_out, int out_size, void* d_ws, size_t ws_size,
                              hipStream_t stream) {
  const float* x = (const float*)d_in[0];
  const int* ei = (const int*)d_in[1];
  const float* ew = (const float*)d_in[2];
  const float* Wself = (const float*)d_in[3];
  const float* Wneigh = (const float*)d_in[4];
  const float* bias = (const float*)d_in[5];
  float* out = (float*)d_out;

  const int N = in_sizes[0] / IN_F;
  const int E = in_sizes[2];

  // d_ws layout: num [N*256 f32] | wsum [N f32] | Wt [512*256 f32] | flag [int]
  float* num = (float*)d_ws;
  float* wsum = num + (size_t)N * IN_F;
  float* Wt = wsum + N;
  int* flag = (int*)(Wt + (size_t)K_TOT * IN_F);

  hipMemsetAsync(d_ws, 0, (size_t)(N * IN_F + N) * sizeof(float), stream);

  detect_i64_kernel<<<1, 256, 0, stream>>>(ei, flag);

  build_wt_kernel<<<(K_TOT * IN_F) / 256, 256, 0, stream>>>(Wself, Wneigh, Wt);

  int scatter_blocks = (E + 3) / 4;  // 4 edges (waves) per 256-thread block
  scatter_kernel<<<scatter_blocks, 256, 0, stream>>>(x, ei, ew, num, wsum, flag, E);

  gemm_norm_kernel<<<(N + BM - 1) / BM, 256, 0, stream>>>(x, num, wsum, Wt, bias,
                                                          out, N);
}

// Round 4
// 922.304 us; speedup vs baseline: 6.2158x; 6.2158x over previous
//
#include <hip/hip_runtime.h>
#include <hip/hip_bf16.h>

#define IN_F 256
#define K_TOT 512
#define BM 32
#define BK 16

// Wt[k][j]: k<256 -> W_self[j][k], else W_neigh[j][k-256]  (512x256 f32)
__global__ void build_wt_kernel(const float* __restrict__ Ws,
                                const float* __restrict__ Wn,
                                float* __restrict__ Wt) {
  int idx = blockIdx.x * 256 + threadIdx.x;
  int k = idx >> 8;
  int j = idx & 255;
  float v = (k < IN_F) ? Ws[j * IN_F + k] : Wn[j * IN_F + (k - IN_F)];
  Wt[idx] = v;
}

// int64 vs int32 edge_index layout detection (robustness; costs ~5us).
__global__ void detect_i64_kernel(const int* __restrict__ ei, int* __restrict__ flag) {
  __shared__ int bad_s[256];
  int t = threadIdx.x;
  int bad = 0;
#pragma unroll
  for (int p = 0; p < 8; ++p) {
    int i = t + p * 256;
    if (ei[2 * i + 1] != 0) bad = 1;
  }
  bad_s[t] = bad;
  __syncthreads();
  for (int s = 128; s > 0; s >>= 1) {
    if (t < s) bad_s[t] |= bad_s[t + s];
    __syncthreads();
  }
  if (t == 0) *flag = (bad_s[0] == 0) ? 1 : 0;  // 1 => int64 layout
}

__global__ void hist_kernel(const int* __restrict__ ei, const int* __restrict__ flag,
                            int* __restrict__ counts, int E) {
  int e = blockIdx.x * 256 + threadIdx.x;
  if (e >= E) return;
  int is64 = *flag;
  int dst = is64 ? ei[2 * (E + e)] : ei[E + e];
  atomicAdd(counts + dst, 1);
}

// Single-block exclusive scan over counts[N] -> offsets[N+1] and cursor[N].
__global__ void scan_kernel(const int* __restrict__ counts,
                            int* __restrict__ offsets,
                            int* __restrict__ cursor, int N, int E) {
  __shared__ int buf[1024];
  __shared__ int carry_s;
  int t = threadIdx.x;
  if (t == 0) carry_s = 0;
  __syncthreads();
  for (int base = 0; base < N; base += 1024) {
    int i = base + t;
    int v = (i < N) ? counts[i] : 0;
    buf[t] = v;
    __syncthreads();
    for (int s = 1; s < 1024; s <<= 1) {
      int add = (t >= s) ? buf[t - s] : 0;
      __syncthreads();
      buf[t] += add;
      __syncthreads();
    }
    int incl = buf[t];
    int excl = incl - v;
    int carry = carry_s;
    if (i < N) {
      offsets[i] = carry + excl;
      cursor[i] = carry + excl;
    }
    __syncthreads();
    if (t == 1023) carry_s = carry + incl;
    __syncthreads();
  }
  if (t == 0) offsets[N] = E;
}

__global__ void fill_kernel(const int* __restrict__ ei, const float* __restrict__ ew,
                            const int* __restrict__ flag, int* __restrict__ cursor,
                            int* __restrict__ ssrc, float* __restrict__ sw, int E) {
  int e = blockIdx.x * 256 + threadIdx.x;
  if (e >= E) return;
  int is64 = *flag;
  int src = is64 ? ei[2 * e] : ei[e];
  int dst = is64 ? ei[2 * (E + e)] : ei[E + e];
  int pos = atomicAdd(cursor + dst, 1);
  ssrc[pos] = src;
  sw[pos] = ew[e];
}

// One wave per dst node: lane owns float4 (4 of 256 feats). Serial register
// accumulation over the node's CSR edge list; weighted-mean applied here.
__launch_bounds__(256)
__global__ void aggregate_kernel(const float* __restrict__ x,
                                 const int* __restrict__ offsets,
                                 const int* __restrict__ ssrc,
                                 const float* __restrict__ sw,
                                 float* __restrict__ neigh, int N) {
  int wid = blockIdx.x * 4 + (threadIdx.x >> 6);
  if (wid >= N) return;
  int lane = threadIdx.x & 63;
  int beg = offsets[wid];
  int end = offsets[wid + 1];
  const float4* x4 = reinterpret_cast<const float4*>(x);
  float4 acc = {0.f, 0.f, 0.f, 0.f};
  float ws = 0.f;
  int e = beg;
  // 2-deep software pipeline for gather-latency ILP
  for (; e + 1 < end; e += 2) {
    int s0 = ssrc[e], s1 = ssrc[e + 1];
    float w0 = sw[e], w1 = sw[e + 1];
    float4 v0 = x4[(size_t)s0 * 64 + lane];
    float4 v1 = x4[(size_t)s1 * 64 + lane];
    acc.x += v0.x * w0 + v1.x * w1;
    acc.y += v0.y * w0 + v1.y * w1;
    acc.z += v0.z * w0 + v1.z * w1;
    acc.w += v0.w * w0 + v1.w * w1;
    ws += w0 + w1;
  }
  if (e < end) {
    int s0 = ssrc[e];
    float w0 = sw[e];
    float4 v0 = x4[(size_t)s0 * 64 + lane];
    acc.x += v0.x * w0;
    acc.y += v0.y * w0;
    acc.z += v0.z * w0;
    acc.w += v0.w * w0;
    ws += w0;
  }
  float inv = 1.f / fmaxf(ws, 1e-8f);
  float4 o = {acc.x * inv, acc.y * inv, acc.z * inv, acc.w * inv};
  reinterpret_cast<float4*>(neigh)[(size_t)wid * 64 + lane] = o;
}

// C[32 x 256] per block; 4 waves, wave w rows w*8..w*8+7, lane cols lane*4+..
__launch_bounds__(256)
__global__ void gemm_norm_kernel(const float* __restrict__ x,
                                 const float* __restrict__ neigh,
                                 const float* __restrict__ Wt,
                                 const float* __restrict__ bias,
                                 float* __restrict__ out, int N) {
  const int t = threadIdx.x;
  const int lane = t & 63;
  const int w = t >> 6;
  const int row0 = blockIdx.x * BM;

  __shared__ float As[BK][BM + 4];
  __shared__ float Bs[BK * IN_F];

  float acc[8][4];
#pragma unroll
  for (int r = 0; r < 8; ++r)
#pragma unroll
    for (int c = 0; c < 4; ++c) acc[r][c] = 0.0f;

  const float4* Wt4 = reinterpret_cast<const float4*>(Wt);
  float4* Bs4 = reinterpret_cast<float4*>(Bs);

  for (int k0 = 0; k0 < K_TOT; k0 += BK) {
#pragma unroll
    for (int p = 0; p < 4; ++p)
      Bs4[p * 256 + t] = Wt4[(k0 << 6) + p * 256 + t];
    {
      int r = t >> 3;
      int kk = (t & 7) << 1;
      int k = k0 + kk;
      int gr = row0 + r;
      int grc = (gr < N) ? gr : (N - 1);
      const float* srcp = (k < IN_F) ? (x + (size_t)grc * IN_F + k)
                                     : (neigh + (size_t)grc * IN_F + (k - IN_F));
      const float2 v = *reinterpret_cast<const float2*>(srcp);
      As[kk][r] = v.x;
      As[kk + 1][r] = v.y;
    }
    __syncthreads();
#pragma unroll
    for (int kk = 0; kk < BK; ++kk) {
      float bf[4], af[8];
      *reinterpret_cast<float4*>(&bf[0]) =
          *reinterpret_cast<const float4*>(&Bs[kk * IN_F + lane * 4]);
      *reinterpret_cast<float4*>(&af[0]) =
          *reinterpret_cast<const float4*>(&As[kk][w * 8]);
      *reinterpret_cast<float4*>(&af[4]) =
          *reinterpret_cast<const float4*>(&As[kk][w * 8 + 4]);
#pragma unroll
      for (int r = 0; r < 8; ++r)
#pragma unroll
        for (int c = 0; c < 4; ++c) acc[r][c] += af[r] * bf[c];
    }
    __syncthreads();
  }

  float bf[4];
  *reinterpret_cast<float4*>(&bf[0]) = reinterpret_cast<const float4*>(bias)[lane];

#pragma unroll
  for (int r = 0; r < 8; ++r) {
    float ss = 0.0f;
#pragma unroll
    for (int c = 0; c < 4; ++c) {
      float v = acc[r][c] + bf[c];
      acc[r][c] = v;
      ss += v * v;
    }
#pragma unroll
    for (int s = 1; s < 64; s <<= 1) ss += __shfl_xor(ss, s, 64);
    int gr = row0 + w * 8 + r;
    if (gr < N) {
      float scale = 1.0f / fmaxf(sqrtf(ss), 1e-12f);
      float4 st;
      st.x = acc[r][0] * scale;
      st.y = acc[r][1] * scale;
      st.z = acc[r][2] * scale;
      st.w = acc[r][3] * scale;
      *reinterpret_cast<float4*>(out + (size_t)gr * IN_F + lane * 4) = st;
    }
  }
}

extern "C" void kernel_launch(void* const* d_in, const int* in_sizes, int n_in,
                              void* d_out, int out_size, void* d_ws, size_t ws_size,
                              hipStream_t stream) {
  const float* x = (const float*)d_in[0];
  const int* ei = (const int*)d_in[1];
  const float* ew = (const float*)d_in[2];
  const float* Wself = (const float*)d_in[3];
  const float* Wneigh = (const float*)d_in[4];
  const float* bias = (const float*)d_in[5];
  float* out = (float*)d_out;

  const int N = in_sizes[0] / IN_F;
  const int E = in_sizes[2];

  // ws layout: neigh[N*256 f32] | Wt[512*256 f32] | counts[N] | offsets[N+1] |
  //            cursor[N] | ssrc[E] | sw[E f32] | flag
  float* neigh = (float*)d_ws;
  float* Wt = neigh + (size_t)N * IN_F;
  int* counts = (int*)(Wt + (size_t)K_TOT * IN_F);
  int* offsets = counts + N;
  int* cursor = offsets + (N + 1);
  int* ssrc = cursor + N;
  float* sw = (float*)(ssrc + E);
  int* flag = (int*)(sw + E);

  hipMemsetAsync(counts, 0, (size_t)N * sizeof(int), stream);

  detect_i64_kernel<<<1, 256, 0, stream>>>(ei, flag);
  build_wt_kernel<<<(K_TOT * IN_F) / 256, 256, 0, stream>>>(Wself, Wneigh, Wt);
  hist_kernel<<<(E + 255) / 256, 256, 0, stream>>>(ei, flag, counts, E);
  scan_kernel<<<1, 1024, 0, stream>>>(counts, offsets, cursor, N, E);
  fill_kernel<<<(E + 255) / 256, 256, 0, stream>>>(ei, ew, flag, cursor, ssrc, sw, E);
  aggregate_kernel<<<(N + 3) / 4, 256, 0, stream>>>(x, offsets, ssrc, sw, neigh, N);
  gemm_norm_kernel<<<(N + BM - 1) / BM, 256, 0, stream>>>(x, neigh, Wt, bias, out, N);
}

// Round 5
// 544.043 us; speedup vs baseline: 10.5374x; 1.6953x over previous
//
#include <hip/hip_runtime.h>
#include <hip/hip_bf16.h>

#define IN_F 256
#define K_TOT 512
#define GR 64   // rows per gemm block
#define GK 32   // k chunk (one MFMA k-step)

typedef __attribute__((ext_vector_type(8))) _Float16 f16x8;
typedef __attribute__((ext_vector_type(4))) _Float16 f16x4;
typedef __attribute__((ext_vector_type(4))) float f32x4;

// Pre-split weights into staged hi/lo f16 layout:
// B*[t][j][kk] where t=k/32 (kstep), j=out col, kk=k%32. Makes GEMM B-staging
// a linear 16KB copy per kstep. W(k,j) = k<256 ? W_self[j][k] : W_neigh[j][k-256].
__global__ void build_w_kernel(const float* __restrict__ Ws,
                               const float* __restrict__ Wn,
                               _Float16* __restrict__ Bhi,
                               _Float16* __restrict__ Blo) {
  int idx = blockIdx.x * 256 + threadIdx.x;  // 0..131071
  int j = idx >> 9;
  int k = idx & 511;
  float v = (k < IN_F) ? Ws[j * IN_F + k] : Wn[j * IN_F + (k - IN_F)];
  _Float16 hi = (_Float16)v;
  _Float16 lo = (_Float16)(v - (float)hi);
  size_t addr = ((size_t)(k >> 5) * 256 + j) * 32 + (k & 31);
  Bhi[addr] = hi;
  Blo[addr] = lo;
}

// int64 vs int32 edge_index layout detection (robustness; ~5us).
__global__ void detect_i64_kernel(const int* __restrict__ ei, int* __restrict__ flag) {
  __shared__ int bad_s[256];
  int t = threadIdx.x;
  int bad = 0;
#pragma unroll
  for (int p = 0; p < 8; ++p) {
    int i = t + p * 256;
    if (ei[2 * i + 1] != 0) bad = 1;
  }
  bad_s[t] = bad;
  __syncthreads();
  for (int s = 128; s > 0; s >>= 1) {
    if (t < s) bad_s[t] |= bad_s[t + s];
    __syncthreads();
  }
  if (t == 0) *flag = (bad_s[0] == 0) ? 1 : 0;
}

__global__ void hist_kernel(const int* __restrict__ ei, const int* __restrict__ flag,
                            int* __restrict__ counts, int E) {
  int e = blockIdx.x * 256 + threadIdx.x;
  if (e >= E) return;
  int is64 = *flag;
  int dst = is64 ? ei[2 * (E + e)] : ei[E + e];
  atomicAdd(counts + dst, 1);
}

// Device-wide scan, 3 kernels. scan1: per-1024-chunk exclusive scan + chunk sum.
__global__ void scan1_kernel(const int* __restrict__ counts, int* __restrict__ offsets,
                             int* __restrict__ bsums, int N) {
  __shared__ int buf[1024];
  int t = threadIdx.x;
  int i = blockIdx.x * 1024 + t;
  int v = (i < N) ? counts[i] : 0;
  buf[t] = v;
  __syncthreads();
  for (int s = 1; s < 1024; s <<= 1) {
    int add = (t >= s) ? buf[t - s] : 0;
    __syncthreads();
    buf[t] += add;
    __syncthreads();
  }
  if (i < N) offsets[i] = buf[t] - v;
  if (t == 1023) bsums[blockIdx.x] = buf[1023];
}

__global__ void scan2_kernel(int* __restrict__ bsums, int nb) {
  __shared__ int buf[128];
  int t = threadIdx.x;
  int v = (t < nb) ? bsums[t] : 0;
  buf[t] = v;
  __syncthreads();
  for (int s = 1; s < 128; s <<= 1) {
    int add = (t >= s) ? buf[t - s] : 0;
    __syncthreads();
    buf[t] += add;
    __syncthreads();
  }
  if (t < nb) bsums[t] = buf[t] - v;  // exclusive
}

__global__ void scan3_kernel(int* __restrict__ offsets, const int* __restrict__ bsums,
                             int* __restrict__ cursor, int N, int E) {
  int i = blockIdx.x * 256 + threadIdx.x;
  if (i < N) {
    int o = offsets[i] + bsums[i >> 10];
    offsets[i] = o;
    cursor[i] = o;
  }
  if (i == 0) offsets[N] = E;
}

__global__ void fill_kernel(const int* __restrict__ ei, const float* __restrict__ ew,
                            const int* __restrict__ flag, int* __restrict__ cursor,
                            int* __restrict__ ssrc, float* __restrict__ sw, int E) {
  int e = blockIdx.x * 256 + threadIdx.x;
  if (e >= E) return;
  int is64 = *flag;
  int src = is64 ? ei[2 * e] : ei[e];
  int dst = is64 ? ei[2 * (E + e)] : ei[E + e];
  int pos = atomicAdd(cursor + dst, 1);
  ssrc[pos] = src;
  sw[pos] = ew[e];
}

// One wave per dst node: lane owns float4 (4 of 256 feats).
__launch_bounds__(256)
__global__ void aggregate_kernel(const float* __restrict__ x,
                                 const int* __restrict__ offsets,
                                 const int* __restrict__ ssrc,
                                 const float* __restrict__ sw,
                                 float* __restrict__ neigh, int N) {
  int wid = blockIdx.x * 4 + (threadIdx.x >> 6);
  if (wid >= N) return;
  int lane = threadIdx.x & 63;
  int beg = offsets[wid];
  int end = offsets[wid + 1];
  const float4* x4 = reinterpret_cast<const float4*>(x);
  float4 acc = {0.f, 0.f, 0.f, 0.f};
  float ws = 0.f;
  int e = beg;
  for (; e + 1 < end; e += 2) {
    int s0 = ssrc[e], s1 = ssrc[e + 1];
    float w0 = sw[e], w1 = sw[e + 1];
    float4 v0 = x4[(size_t)s0 * 64 + lane];
    float4 v1 = x4[(size_t)s1 * 64 + lane];
    acc.x += v0.x * w0 + v1.x * w1;
    acc.y += v0.y * w0 + v1.y * w1;
    acc.z += v0.z * w0 + v1.z * w1;
    acc.w += v0.w * w0 + v1.w * w1;
    ws += w0 + w1;
  }
  if (e < end) {
    int s0 = ssrc[e];
    float w0 = sw[e];
    float4 v0 = x4[(size_t)s0 * 64 + lane];
    acc.x += v0.x * w0;
    acc.y += v0.y * w0;
    acc.z += v0.z * w0;
    acc.w += v0.w * w0;
    ws += w0;
  }
  float inv = 1.f / fmaxf(ws, 1e-8f);
  float4 o = {acc.x * inv, acc.y * inv, acc.z * inv, acc.w * inv};
  reinterpret_cast<float4*>(neigh)[(size_t)wid * 64 + lane] = o;
}

// MFMA GEMM + L2-norm. Block: 64 rows x 256 cols, 4 waves; wave w owns cols
// [w*64, w*64+64) (4 coltiles x 4 rowtiles of 16x16). f16 hi/lo split:
// A*B ~ Ah*Bh + Ah*Bl + Al*Bh (rel err ~2^-22). K loop: 16 steps of 32.
// LDS rows padded to 40 halves (80B = 20 banks -> 2-way, free).
__launch_bounds__(256)
__global__ void gemm_norm_kernel(const float* __restrict__ x,
                                 const float* __restrict__ neigh,
                                 const _Float16* __restrict__ Bhi,
                                 const _Float16* __restrict__ Blo,
                                 const float* __restrict__ bias,
                                 float* __restrict__ out, int N) {
  const int t = threadIdx.x;
  const int lane = t & 63;
  const int w = t >> 6;
  const int row0 = blockIdx.x * GR;

  __shared__ _Float16 Ah[GR * 40];
  __shared__ _Float16 Al[GR * 40];
  __shared__ _Float16 Bh[256 * 40];
  __shared__ _Float16 Bl[256 * 40];
  __shared__ float ssb[GR][4];

  f32x4 acc[4][4];
#pragma unroll
  for (int rt = 0; rt < 4; ++rt)
#pragma unroll
    for (int ct = 0; ct < 4; ++ct) acc[rt][ct] = (f32x4){0.f, 0.f, 0.f, 0.f};

  const int4* Bhi4 = reinterpret_cast<const int4*>(Bhi);
  const int4* Blo4 = reinterpret_cast<const int4*>(Blo);

  for (int ks = 0; ks < 16; ++ks) {
    const int k0 = ks * GK;
    const float* __restrict__ A = (k0 < IN_F) ? x : neigh;
    const int kbase = k0 & (IN_F - 1);
    // --- stage A (64 rows x 32 k f32 -> hi/lo f16 LDS) ---
#pragma unroll
    for (int p = 0; p < 2; ++p) {
      int q = p * 256 + t;
      int r = q >> 3, seg = q & 7;
      int gr = row0 + r;
      if (gr >= N) gr = N - 1;
      float4 v = *reinterpret_cast<const float4*>(A + (size_t)gr * IN_F + kbase + seg * 4);
      _Float16 h0 = (_Float16)v.x, h1 = (_Float16)v.y, h2 = (_Float16)v.z, h3 = (_Float16)v.w;
      f16x4 hv = {h0, h1, h2, h3};
      f16x4 lv = {(_Float16)(v.x - (float)h0), (_Float16)(v.y - (float)h1),
                  (_Float16)(v.z - (float)h2), (_Float16)(v.w - (float)h3)};
      *reinterpret_cast<f16x4*>(&Ah[r * 40 + seg * 4]) = hv;
      *reinterpret_cast<f16x4*>(&Al[r * 40 + seg * 4]) = lv;
    }
    // --- stage B (256 cols x 32 k, hi+lo; linear 16KB copies) ---
#pragma unroll
    for (int p = 0; p < 4; ++p) {
      int g = p * 256 + t;
      int col = g >> 2, seg = g & 3;
      int srci = (ks * 256 + col) * 4 + seg;
      int4 vh = Bhi4[srci];
      int4 vl = Blo4[srci];
      *reinterpret_cast<int4*>(&Bh[col * 40 + seg * 8]) = vh;
      *reinterpret_cast<int4*>(&Bl[col * 40 + seg * 8]) = vl;
    }
    __syncthreads();
    // --- fragments + MFMA ---
    f16x8 aH[4], aL[4];
#pragma unroll
    for (int rt = 0; rt < 4; ++rt) {
      int ao = (rt * 16 + (lane & 15)) * 40 + (lane >> 4) * 8;
      aH[rt] = *reinterpret_cast<const f16x8*>(&Ah[ao]);
      aL[rt] = *reinterpret_cast<const f16x8*>(&Al[ao]);
    }
#pragma unroll
    for (int ct = 0; ct < 4; ++ct) {
      int bo = (w * 64 + ct * 16 + (lane & 15)) * 40 + (lane >> 4) * 8;
      f16x8 bH = *reinterpret_cast<const f16x8*>(&Bh[bo]);
      f16x8 bL = *reinterpret_cast<const f16x8*>(&Bl[bo]);
#pragma unroll
      for (int rt = 0; rt < 4; ++rt) {
        acc[rt][ct] = __builtin_amdgcn_mfma_f32_16x16x32_f16(aH[rt], bH, acc[rt][ct], 0, 0, 0);
        acc[rt][ct] = __builtin_amdgcn_mfma_f32_16x16x32_f16(aH[rt], bL, acc[rt][ct], 0, 0, 0);
        acc[rt][ct] = __builtin_amdgcn_mfma_f32_16x16x32_f16(aL[rt], bH, acc[rt][ct], 0, 0, 0);
      }
    }
    __syncthreads();
  }

  // --- epilogue: bias, row sumsq (16-lane xor reduce + cross-wave LDS), norm ---
  float bv[4];
#pragma unroll
  for (int ct = 0; ct < 4; ++ct) bv[ct] = bias[w * 64 + ct * 16 + (lane & 15)];

#pragma unroll
  for (int rt = 0; rt < 4; ++rt)
#pragma unroll
    for (int i = 0; i < 4; ++i) {
      float ssv = 0.f;
#pragma unroll
      for (int ct = 0; ct < 4; ++ct) {
        float val = acc[rt][ct][i] + bv[ct];
        acc[rt][ct][i] = val;
        ssv += val * val;
      }
#pragma unroll
      for (int s = 1; s < 16; s <<= 1) ssv += __shfl_xor(ssv, s, 64);
      if ((lane & 15) == 0) ssb[rt * 16 + (lane >> 4) * 4 + i][w] = ssv;
    }
  __syncthreads();

#pragma unroll
  for (int rt = 0; rt < 4; ++rt)
#pragma unroll
    for (int i = 0; i < 4; ++i) {
      int rl = rt * 16 + (lane >> 4) * 4 + i;
      f32x4 s4 = *reinterpret_cast<const f32x4*>(&ssb[rl][0]);
      float ss = s4[0] + s4[1] + s4[2] + s4[3];
      int gr = row0 + rl;
      if (gr < N) {
        float scale = 1.0f / fmaxf(sqrtf(ss), 1e-12f);
#pragma unroll
        for (int ct = 0; ct < 4; ++ct)
          out[(size_t)gr * IN_F + w * 64 + ct * 16 + (lane & 15)] = acc[rt][ct][i] * scale;
      }
    }
}

extern "C" void kernel_launch(void* const* d_in, const int* in_sizes, int n_in,
                              void* d_out, int out_size, void* d_ws, size_t ws_size,
                              hipStream_t stream) {
  const float* x = (const float*)d_in[0];
  const int* ei = (const int*)d_in[1];
  const float* ew = (const float*)d_in[2];
  const float* Wself = (const float*)d_in[3];
  const float* Wneigh = (const float*)d_in[4];
  const float* bias = (const float*)d_in[5];
  float* out = (float*)d_out;

  const int N = in_sizes[0] / IN_F;
  const int E = in_sizes[2];

  // ws: neigh[N*256 f32] | Bhi[512*256 f16] | Blo[...] | counts[N] | offsets[N+1]
  //     | cursor[N] | bsums[128] | ssrc[E] | sw[E] | flag
  float* neigh = (float*)d_ws;
  _Float16* Bhi = (_Float16*)(neigh + (size_t)N * IN_F);
  _Float16* Blo = Bhi + (size_t)K_TOT * IN_F;
  int* counts = (int*)(Blo + (size_t)K_TOT * IN_F);
  int* offsets = counts + N;
  int* cursor = offsets + (N + 1);
  int* bsums = cursor + N;
  int* ssrc = bsums + 128;
  float* sw = (float*)(ssrc + E);
  int* flag = (int*)(sw + E);

  const int nb = (N + 1023) / 1024;

  hipMemsetAsync(counts, 0, (size_t)N * sizeof(int), stream);

  detect_i64_kernel<<<1, 256, 0, stream>>>(ei, flag);
  build_w_kernel<<<(K_TOT * IN_F) / 256, 256, 0, stream>>>(Wself, Wneigh, Bhi, Blo);
  hist_kernel<<<(E + 255) / 256, 256, 0, stream>>>(ei, flag, counts, E);
  scan1_kernel<<<nb, 1024, 0, stream>>>(counts, offsets, bsums, N);
  scan2_kernel<<<1, 128, 0, stream>>>(bsums, nb);
  scan3_kernel<<<(N + 255) / 256, 256, 0, stream>>>(offsets, bsums, cursor, N, E);
  fill_kernel<<<(E + 255) / 256, 256, 0, stream>>>(ei, ew, flag, cursor, ssrc, sw, E);
  aggregate_kernel<<<(N + 3) / 4, 256, 0, stream>>>(x, offsets, ssrc, sw, neigh, N);
  gemm_norm_kernel<<<(N + GR - 1) / GR, 256, 0, stream>>>(x, neigh, Bhi, Blo, bias, out, N);
}

// Round 6
// 517.301 us; speedup vs baseline: 11.0822x; 1.0517x over previous
//
#include <hip/hip_runtime.h>
#include <hip/hip_bf16.h>

#define IN_F 256
#define K_TOT 512
#define GR 64   // rows per gemm block
#define GK 32   // k chunk (one MFMA k-step)

typedef __attribute__((ext_vector_type(8))) _Float16 f16x8;
typedef __attribute__((ext_vector_type(4))) _Float16 f16x4;
typedef __attribute__((ext_vector_type(4))) float f32x4;

// Pre-split weights into staged hi/lo f16 layout:
// B*[t][j][kk], t=k/32 kstep, j=out col, kk=k%32 -> linear 16KB GEMM staging.
__global__ void build_w_kernel(const float* __restrict__ Ws,
                               const float* __restrict__ Wn,
                               _Float16* __restrict__ Bhi,
                               _Float16* __restrict__ Blo) {
  int idx = blockIdx.x * 256 + threadIdx.x;  // 0..131071
  int j = idx >> 9;
  int k = idx & 511;
  float v = (k < IN_F) ? Ws[j * IN_F + k] : Wn[j * IN_F + (k - IN_F)];
  _Float16 hi = (_Float16)v;
  _Float16 lo = (_Float16)(v - (float)hi);
  size_t addr = ((size_t)(k >> 5) * 256 + j) * 32 + (k & 31);
  Bhi[addr] = hi;
  Blo[addr] = lo;
}

// x f32 -> f16 copy (halves gather traffic; 51MB L3-resident working set)
__global__ void convert_x_kernel(const float* __restrict__ x,
                                 _Float16* __restrict__ xh, int total8) {
  int i = blockIdx.x * 256 + threadIdx.x;
  if (i >= total8) return;
  const float4* x4 = reinterpret_cast<const float4*>(x);
  float4 a = x4[(size_t)i * 2], b = x4[(size_t)i * 2 + 1];
  f16x8 o = {(_Float16)a.x, (_Float16)a.y, (_Float16)a.z, (_Float16)a.w,
             (_Float16)b.x, (_Float16)b.y, (_Float16)b.z, (_Float16)b.w};
  *reinterpret_cast<f16x8*>(xh + (size_t)i * 8) = o;
}

// int64 vs int32 edge_index layout detection (robustness; ~5us).
__global__ void detect_i64_kernel(const int* __restrict__ ei, int* __restrict__ flag) {
  __shared__ int bad_s[256];
  int t = threadIdx.x;
  int bad = 0;
#pragma unroll
  for (int p = 0; p < 8; ++p) {
    int i = t + p * 256;
    if (ei[2 * i + 1] != 0) bad = 1;
  }
  bad_s[t] = bad;
  __syncthreads();
  for (int s = 128; s > 0; s >>= 1) {
    if (t < s) bad_s[t] |= bad_s[t + s];
    __syncthreads();
  }
  if (t == 0) *flag = (bad_s[0] == 0) ? 1 : 0;
}

__global__ void hist_kernel(const int* __restrict__ ei, const int* __restrict__ flag,
                            int* __restrict__ counts, int E) {
  int e = blockIdx.x * 256 + threadIdx.x;
  if (e >= E) return;
  int is64 = *flag;
  int dst = is64 ? ei[2 * (E + e)] : ei[E + e];
  atomicAdd(counts + dst, 1);
}

__global__ void scan1_kernel(const int* __restrict__ counts, int* __restrict__ offsets,
                             int* __restrict__ bsums, int N) {
  __shared__ int buf[1024];
  int t = threadIdx.x;
  int i = blockIdx.x * 1024 + t;
  int v = (i < N) ? counts[i] : 0;
  buf[t] = v;
  __syncthreads();
  for (int s = 1; s < 1024; s <<= 1) {
    int add = (t >= s) ? buf[t - s] : 0;
    __syncthreads();
    buf[t] += add;
    __syncthreads();
  }
  if (i < N) offsets[i] = buf[t] - v;
  if (t == 1023) bsums[blockIdx.x] = buf[1023];
}

__global__ void scan2_kernel(int* __restrict__ bsums, int nb) {
  __shared__ int buf[128];
  int t = threadIdx.x;
  int v = (t < nb) ? bsums[t] : 0;
  buf[t] = v;
  __syncthreads();
  for (int s = 1; s < 128; s <<= 1) {
    int add = (t >= s) ? buf[t - s] : 0;
    __syncthreads();
    buf[t] += add;
    __syncthreads();
  }
  if (t < nb) bsums[t] = buf[t] - v;  // exclusive
}

__global__ void scan3_kernel(int* __restrict__ offsets, const int* __restrict__ bsums,
                             int* __restrict__ cursor, int N, int E) {
  int i = blockIdx.x * 256 + threadIdx.x;
  if (i < N) {
    int o = offsets[i] + bsums[i >> 10];
    offsets[i] = o;
    cursor[i] = o;
  }
  if (i == 0) offsets[N] = E;
}

// CSR fill with packed (src, weight-bits) payload: one 8B random store.
__global__ void fill_kernel(const int* __restrict__ ei, const float* __restrict__ ew,
                            const int* __restrict__ flag, int* __restrict__ cursor,
                            int2* __restrict__ edges, int E) {
  int e = blockIdx.x * 256 + threadIdx.x;
  if (e >= E) return;
  int is64 = *flag;
  int src = is64 ? ei[2 * e] : ei[e];
  int dst = is64 ? ei[2 * (E + e)] : ei[E + e];
  int pos = atomicAdd(cursor + dst, 1);
  edges[pos] = make_int2(src, __float_as_int(ew[e]));
}

// One wave per dst node, f16 gather (8B/lane), 4-deep pipeline.
__launch_bounds__(256)
__global__ void aggregate_f16_kernel(const _Float16* __restrict__ xh,
                                     const int* __restrict__ offsets,
                                     const int2* __restrict__ edges,
                                     float* __restrict__ neigh, int N) {
  int wid = blockIdx.x * 4 + (threadIdx.x >> 6);
  if (wid >= N) return;
  int lane = threadIdx.x & 63;
  int beg = offsets[wid];
  int end = offsets[wid + 1];
  float4 acc = {0.f, 0.f, 0.f, 0.f};
  float ws = 0.f;
  int e = beg;
  for (; e + 3 < end; e += 4) {
    int2 e0 = edges[e], e1 = edges[e + 1], e2 = edges[e + 2], e3 = edges[e + 3];
    float w0 = __int_as_float(e0.y), w1 = __int_as_float(e1.y);
    float w2 = __int_as_float(e2.y), w3 = __int_as_float(e3.y);
    f16x4 v0 = *reinterpret_cast<const f16x4*>(xh + (size_t)e0.x * IN_F + lane * 4);
    f16x4 v1 = *reinterpret_cast<const f16x4*>(xh + (size_t)e1.x * IN_F + lane * 4);
    f16x4 v2 = *reinterpret_cast<const f16x4*>(xh + (size_t)e2.x * IN_F + lane * 4);
    f16x4 v3 = *reinterpret_cast<const f16x4*>(xh + (size_t)e3.x * IN_F + lane * 4);
#pragma unroll
    for (int c = 0; c < 4; ++c) {
      float s = (float)v0[c] * w0 + (float)v1[c] * w1 + (float)v2[c] * w2 +
                (float)v3[c] * w3;
      (&acc.x)[c] += s;
    }
    ws += w0 + w1 + w2 + w3;
  }
  for (; e < end; ++e) {
    int2 e0 = edges[e];
    float w0 = __int_as_float(e0.y);
    f16x4 v0 = *reinterpret_cast<const f16x4*>(xh + (size_t)e0.x * IN_F + lane * 4);
#pragma unroll
    for (int c = 0; c < 4; ++c) (&acc.x)[c] += (float)v0[c] * w0;
    ws += w0;
  }
  float inv = 1.f / fmaxf(ws, 1e-8f);
  float4 o = {acc.x * inv, acc.y * inv, acc.z * inv, acc.w * inv};
  reinterpret_cast<float4*>(neigh)[(size_t)wid * 64 + lane] = o;
}

// Fallback: f32 gather (if ws too small for xh copy).
__launch_bounds__(256)
__global__ void aggregate_f32_kernel(const float* __restrict__ x,
                                     const int* __restrict__ offsets,
                                     const int2* __restrict__ edges,
                                     float* __restrict__ neigh, int N) {
  int wid = blockIdx.x * 4 + (threadIdx.x >> 6);
  if (wid >= N) return;
  int lane = threadIdx.x & 63;
  int beg = offsets[wid];
  int end = offsets[wid + 1];
  const float4* x4 = reinterpret_cast<const float4*>(x);
  float4 acc = {0.f, 0.f, 0.f, 0.f};
  float ws = 0.f;
  int e = beg;
  for (; e + 1 < end; e += 2) {
    int2 e0 = edges[e], e1 = edges[e + 1];
    float w0 = __int_as_float(e0.y), w1 = __int_as_float(e1.y);
    float4 v0 = x4[(size_t)e0.x * 64 + lane];
    float4 v1 = x4[(size_t)e1.x * 64 + lane];
    acc.x += v0.x * w0 + v1.x * w1;
    acc.y += v0.y * w0 + v1.y * w1;
    acc.z += v0.z * w0 + v1.z * w1;
    acc.w += v0.w * w0 + v1.w * w1;
    ws += w0 + w1;
  }
  if (e < end) {
    int2 e0 = edges[e];
    float w0 = __int_as_float(e0.y);
    float4 v0 = x4[(size_t)e0.x * 64 + lane];
    acc.x += v0.x * w0;
    acc.y += v0.y * w0;
    acc.z += v0.z * w0;
    acc.w += v0.w * w0;
    ws += w0;
  }
  float inv = 1.f / fmaxf(ws, 1e-8f);
  float4 o = {acc.x * inv, acc.y * inv, acc.z * inv, acc.w * inv};
  reinterpret_cast<float4*>(neigh)[(size_t)wid * 64 + lane] = o;
}

// MFMA GEMM + L2-norm (unchanged from round 5; passed at absmax 9.8e-4).
__launch_bounds__(256)
__global__ void gemm_norm_kernel(const float* __restrict__ x,
                                 const float* __restrict__ neigh,
                                 const _Float16* __restrict__ Bhi,
                                 const _Float16* __restrict__ Blo,
                                 const float* __restrict__ bias,
                                 float* __restrict__ out, int N) {
  const int t = threadIdx.x;
  const int lane = t & 63;
  const int w = t >> 6;
  const int row0 = blockIdx.x * GR;

  __shared__ _Float16 Ah[GR * 40];
  __shared__ _Float16 Al[GR * 40];
  __shared__ _Float16 Bh[256 * 40];
  __shared__ _Float16 Bl[256 * 40];
  __shared__ float ssb[GR][4];

  f32x4 acc[4][4];
#pragma unroll
  for (int rt = 0; rt < 4; ++rt)
#pragma unroll
    for (int ct = 0; ct < 4; ++ct) acc[rt][ct] = (f32x4){0.f, 0.f, 0.f, 0.f};

  const int4* Bhi4 = reinterpret_cast<const int4*>(Bhi);
  const int4* Blo4 = reinterpret_cast<const int4*>(Blo);

  for (int ks = 0; ks < 16; ++ks) {
    const int k0 = ks * GK;
    const float* __restrict__ A = (k0 < IN_F) ? x : neigh;
    const int kbase = k0 & (IN_F - 1);
#pragma unroll
    for (int p = 0; p < 2; ++p) {
      int q = p * 256 + t;
      int r = q >> 3, seg = q & 7;
      int gr = row0 + r;
      if (gr >= N) gr = N - 1;
      float4 v = *reinterpret_cast<const float4*>(A + (size_t)gr * IN_F + kbase + seg * 4);
      _Float16 h0 = (_Float16)v.x, h1 = (_Float16)v.y, h2 = (_Float16)v.z, h3 = (_Float16)v.w;
      f16x4 hv = {h0, h1, h2, h3};
      f16x4 lv = {(_Float16)(v.x - (float)h0), (_Float16)(v.y - (float)h1),
                  (_Float16)(v.z - (float)h2), (_Float16)(v.w - (float)h3)};
      *reinterpret_cast<f16x4*>(&Ah[r * 40 + seg * 4]) = hv;
      *reinterpret_cast<f16x4*>(&Al[r * 40 + seg * 4]) = lv;
    }
#pragma unroll
    for (int p = 0; p < 4; ++p) {
      int g = p * 256 + t;
      int col = g >> 2, seg = g & 3;
      int srci = (ks * 256 + col) * 4 + seg;
      int4 vh = Bhi4[srci];
      int4 vl = Blo4[srci];
      *reinterpret_cast<int4*>(&Bh[col * 40 + seg * 8]) = vh;
      *reinterpret_cast<int4*>(&Bl[col * 40 + seg * 8]) = vl;
    }
    __syncthreads();
    f16x8 aH[4], aL[4];
#pragma unroll
    for (int rt = 0; rt < 4; ++rt) {
      int ao = (rt * 16 + (lane & 15)) * 40 + (lane >> 4) * 8;
      aH[rt] = *reinterpret_cast<const f16x8*>(&Ah[ao]);
      aL[rt] = *reinterpret_cast<const f16x8*>(&Al[ao]);
    }
#pragma unroll
    for (int ct = 0; ct < 4; ++ct) {
      int bo = (w * 64 + ct * 16 + (lane & 15)) * 40 + (lane >> 4) * 8;
      f16x8 bH = *reinterpret_cast<const f16x8*>(&Bh[bo]);
      f16x8 bL = *reinterpret_cast<const f16x8*>(&Bl[bo]);
#pragma unroll
      for (int rt = 0; rt < 4; ++rt) {
        acc[rt][ct] = __builtin_amdgcn_mfma_f32_16x16x32_f16(aH[rt], bH, acc[rt][ct], 0, 0, 0);
        acc[rt][ct] = __builtin_amdgcn_mfma_f32_16x16x32_f16(aH[rt], bL, acc[rt][ct], 0, 0, 0);
        acc[rt][ct] = __builtin_amdgcn_mfma_f32_16x16x32_f16(aL[rt], bH, acc[rt][ct], 0, 0, 0);
      }
    }
    __syncthreads();
  }

  float bv[4];
#pragma unroll
  for (int ct = 0; ct < 4; ++ct) bv[ct] = bias[w * 64 + ct * 16 + (lane & 15)];

#pragma unroll
  for (int rt = 0; rt < 4; ++rt)
#pragma unroll
    for (int i = 0; i < 4; ++i) {
      float ssv = 0.f;
#pragma unroll
      for (int ct = 0; ct < 4; ++ct) {
        float val = acc[rt][ct][i] + bv[ct];
        acc[rt][ct][i] = val;
        ssv += val * val;
      }
#pragma unroll
      for (int s = 1; s < 16; s <<= 1) ssv += __shfl_xor(ssv, s, 64);
      if ((lane & 15) == 0) ssb[rt * 16 + (lane >> 4) * 4 + i][w] = ssv;
    }
  __syncthreads();

#pragma unroll
  for (int rt = 0; rt < 4; ++rt)
#pragma unroll
    for (int i = 0; i < 4; ++i) {
      int rl = rt * 16 + (lane >> 4) * 4 + i;
      f32x4 s4 = *reinterpret_cast<const f32x4*>(&ssb[rl][0]);
      float ss = s4[0] + s4[1] + s4[2] + s4[3];
      int gr = row0 + rl;
      if (gr < N) {
        float scale = 1.0f / fmaxf(sqrtf(ss), 1e-12f);
#pragma unroll
        for (int ct = 0; ct < 4; ++ct)
          out[(size_t)gr * IN_F + w * 64 + ct * 16 + (lane & 15)] = acc[rt][ct][i] * scale;
      }
    }
}

extern "C" void kernel_launch(void* const* d_in, const int* in_sizes, int n_in,
                              void* d_out, int out_size, void* d_ws, size_t ws_size,
                              hipStream_t stream) {
  const float* x = (const float*)d_in[0];
  const int* ei = (const int*)d_in[1];
  const float* ew = (const float*)d_in[2];
  const float* Wself = (const float*)d_in[3];
  const float* Wneigh = (const float*)d_in[4];
  const float* bias = (const float*)d_in[5];
  float* out = (float*)d_out;

  const int N = in_sizes[0] / IN_F;
  const int E = in_sizes[2];

  // ws: neigh[N*256 f32] | Bhi | Blo | edges[E int2] | counts | offsets | cursor
  //     | bsums[128] | flag | (pad) | xh[N*256 f16]  (xh only if ws allows)
  char* p = (char*)d_ws;
  float* neigh = (float*)p;                 p += (size_t)N * IN_F * 4;
  _Float16* Bhi = (_Float16*)p;             p += (size_t)K_TOT * IN_F * 2;
  _Float16* Blo = (_Float16*)p;             p += (size_t)K_TOT * IN_F * 2;
  int2* edges = (int2*)p;                   p += (size_t)E * 8;
  int* counts = (int*)p;                    p += (size_t)N * 4;
  int* offsets = (int*)p;                   p += (size_t)(N + 1) * 4;
  int* cursor = (int*)p;                    p += (size_t)N * 4;
  int* bsums = (int*)p;                     p += 128 * 4;
  int* flag = (int*)p;                      p += 16;  // keep 16B alignment
  _Float16* xh = (_Float16*)p;              p += (size_t)N * IN_F * 2;

  const bool use_f16 = ((size_t)(p - (char*)d_ws) <= ws_size);
  const int nb = (N + 1023) / 1024;

  hipMemsetAsync(counts, 0, (size_t)N * sizeof(int), stream);

  detect_i64_kernel<<<1, 256, 0, stream>>>(ei, flag);
  build_w_kernel<<<(K_TOT * IN_F) / 256, 256, 0, stream>>>(Wself, Wneigh, Bhi, Blo);
  if (use_f16) {
    int total8 = N * IN_F / 8;
    convert_x_kernel<<<(total8 + 255) / 256, 256, 0, stream>>>(x, xh, total8);
  }
  hist_kernel<<<(E + 255) / 256, 256, 0, stream>>>(ei, flag, counts, E);
  scan1_kernel<<<nb, 1024, 0, stream>>>(counts, offsets, bsums, N);
  scan2_kernel<<<1, 128, 0, stream>>>(bsums, nb);
  scan3_kernel<<<(N + 255) / 256, 256, 0, stream>>>(offsets, bsums, cursor, N, E);
  fill_kernel<<<(E + 255) / 256, 256, 0, stream>>>(ei, ew, flag, cursor, edges, E);
  if (use_f16) {
    aggregate_f16_kernel<<<(N + 3) / 4, 256, 0, stream>>>(xh, offsets, edges, neigh, N);
  } else {
    aggregate_f32_kernel<<<(N + 3) / 4, 256, 0, stream>>>(x, offsets, edges, neigh, N);
  }
  gemm_norm_kernel<<<(N + GR - 1) / GR, 256, 0, stream>>>(x, neigh, Bhi, Blo, bias, out, N);
}

// Round 7
// 491.178 us; speedup vs baseline: 11.6716x; 1.0532x over previous
//
#include <hip/hip_runtime.h>
#include <hip/hip_bf16.h>

#define IN_F 256
#define K_TOT 512
#define GR 64   // rows per gemm block
#define GK 32   // k chunk (one MFMA k-step)

typedef __attribute__((ext_vector_type(8))) _Float16 f16x8;
typedef __attribute__((ext_vector_type(4))) _Float16 f16x4;
typedef __attribute__((ext_vector_type(4))) float f32x4;

// Pre-split weights into staged hi/lo f16 layout:
// B*[t][j][kk], t=k/32 kstep, j=out col, kk=k%32. GEMM loads fragments
// directly from this (L2-resident, 512KB total) -- no LDS staging for B.
__global__ void build_w_kernel(const float* __restrict__ Ws,
                               const float* __restrict__ Wn,
                               _Float16* __restrict__ Bhi,
                               _Float16* __restrict__ Blo) {
  int idx = blockIdx.x * 256 + threadIdx.x;  // 0..131071
  int j = idx >> 9;
  int k = idx & 511;
  float v = (k < IN_F) ? Ws[j * IN_F + k] : Wn[j * IN_F + (k - IN_F)];
  _Float16 hi = (_Float16)v;
  _Float16 lo = (_Float16)(v - (float)hi);
  size_t addr = ((size_t)(k >> 5) * 256 + j) * 32 + (k & 31);
  Bhi[addr] = hi;
  Blo[addr] = lo;
}

// x f32 -> f16 copy (halves gather traffic; 51MB L3-resident working set)
__global__ void convert_x_kernel(const float* __restrict__ x,
                                 _Float16* __restrict__ xh, int total8) {
  int i = blockIdx.x * 256 + threadIdx.x;
  if (i >= total8) return;
  const float4* x4 = reinterpret_cast<const float4*>(x);
  float4 a = x4[(size_t)i * 2], b = x4[(size_t)i * 2 + 1];
  f16x8 o = {(_Float16)a.x, (_Float16)a.y, (_Float16)a.z, (_Float16)a.w,
             (_Float16)b.x, (_Float16)b.y, (_Float16)b.z, (_Float16)b.w};
  *reinterpret_cast<f16x8*>(xh + (size_t)i * 8) = o;
}

// int64 vs int32 edge_index layout detection (robustness; ~5us).
__global__ void detect_i64_kernel(const int* __restrict__ ei, int* __restrict__ flag) {
  __shared__ int bad_s[256];
  int t = threadIdx.x;
  int bad = 0;
#pragma unroll
  for (int p = 0; p < 8; ++p) {
    int i = t + p * 256;
    if (ei[2 * i + 1] != 0) bad = 1;
  }
  bad_s[t] = bad;
  __syncthreads();
  for (int s = 128; s > 0; s >>= 1) {
    if (t < s) bad_s[t] |= bad_s[t + s];
    __syncthreads();
  }
  if (t == 0) *flag = (bad_s[0] == 0) ? 1 : 0;
}

__global__ void hist_kernel(const int* __restrict__ ei, const int* __restrict__ flag,
                            int* __restrict__ counts, int E) {
  int e = blockIdx.x * 256 + threadIdx.x;
  if (e >= E) return;
  int is64 = *flag;
  int dst = is64 ? ei[2 * (E + e)] : ei[E + e];
  atomicAdd(counts + dst, 1);
}

__global__ void scan1_kernel(const int* __restrict__ counts, int* __restrict__ offsets,
                             int* __restrict__ bsums, int N) {
  __shared__ int buf[1024];
  int t = threadIdx.x;
  int i = blockIdx.x * 1024 + t;
  int v = (i < N) ? counts[i] : 0;
  buf[t] = v;
  __syncthreads();
  for (int s = 1; s < 1024; s <<= 1) {
    int add = (t >= s) ? buf[t - s] : 0;
    __syncthreads();
    buf[t] += add;
    __syncthreads();
  }
  if (i < N) offsets[i] = buf[t] - v;
  if (t == 1023) bsums[blockIdx.x] = buf[1023];
}

__global__ void scan2_kernel(int* __restrict__ bsums, int nb) {
  __shared__ int buf[128];
  int t = threadIdx.x;
  int v = (t < nb) ? bsums[t] : 0;
  buf[t] = v;
  __syncthreads();
  for (int s = 1; s < 128; s <<= 1) {
    int add = (t >= s) ? buf[t - s] : 0;
    __syncthreads();
    buf[t] += add;
    __syncthreads();
  }
  if (t < nb) bsums[t] = buf[t] - v;  // exclusive
}

__global__ void scan3_kernel(int* __restrict__ offsets, const int* __restrict__ bsums,
                             int* __restrict__ cursor, int N, int E) {
  int i = blockIdx.x * 256 + threadIdx.x;
  if (i < N) {
    int o = offsets[i] + bsums[i >> 10];
    offsets[i] = o;
    cursor[i] = o;
  }
  if (i == 0) offsets[N] = E;
}

// CSR fill with packed (src, weight-bits) payload: one 8B random store.
__global__ void fill_kernel(const int* __restrict__ ei, const float* __restrict__ ew,
                            const int* __restrict__ flag, int* __restrict__ cursor,
                            int2* __restrict__ edges, int E) {
  int e = blockIdx.x * 256 + threadIdx.x;
  if (e >= E) return;
  int is64 = *flag;
  int src = is64 ? ei[2 * e] : ei[e];
  int dst = is64 ? ei[2 * (E + e)] : ei[E + e];
  int pos = atomicAdd(cursor + dst, 1);
  edges[pos] = make_int2(src, __float_as_int(ew[e]));
}

// One wave per dst node, f16 gather (8B/lane), 4-deep pipeline.
__launch_bounds__(256)
__global__ void aggregate_f16_kernel(const _Float16* __restrict__ xh,
                                     const int* __restrict__ offsets,
                                     const int2* __restrict__ edges,
                                     float* __restrict__ neigh, int N) {
  int wid = blockIdx.x * 4 + (threadIdx.x >> 6);
  if (wid >= N) return;
  int lane = threadIdx.x & 63;
  int beg = offsets[wid];
  int end = offsets[wid + 1];
  float4 acc = {0.f, 0.f, 0.f, 0.f};
  float ws = 0.f;
  int e = beg;
  for (; e + 3 < end; e += 4) {
    int2 e0 = edges[e], e1 = edges[e + 1], e2 = edges[e + 2], e3 = edges[e + 3];
    float w0 = __int_as_float(e0.y), w1 = __int_as_float(e1.y);
    float w2 = __int_as_float(e2.y), w3 = __int_as_float(e3.y);
    f16x4 v0 = *reinterpret_cast<const f16x4*>(xh + (size_t)e0.x * IN_F + lane * 4);
    f16x4 v1 = *reinterpret_cast<const f16x4*>(xh + (size_t)e1.x * IN_F + lane * 4);
    f16x4 v2 = *reinterpret_cast<const f16x4*>(xh + (size_t)e2.x * IN_F + lane * 4);
    f16x4 v3 = *reinterpret_cast<const f16x4*>(xh + (size_t)e3.x * IN_F + lane * 4);
#pragma unroll
    for (int c = 0; c < 4; ++c) {
      float s = (float)v0[c] * w0 + (float)v1[c] * w1 + (float)v2[c] * w2 +
                (float)v3[c] * w3;
      (&acc.x)[c] += s;
    }
    ws += w0 + w1 + w2 + w3;
  }
  for (; e < end; ++e) {
    int2 e0 = edges[e];
    float w0 = __int_as_float(e0.y);
    f16x4 v0 = *reinterpret_cast<const f16x4*>(xh + (size_t)e0.x * IN_F + lane * 4);
#pragma unroll
    for (int c = 0; c < 4; ++c) (&acc.x)[c] += (float)v0[c] * w0;
    ws += w0;
  }
  float inv = 1.f / fmaxf(ws, 1e-8f);
  float4 o = {acc.x * inv, acc.y * inv, acc.z * inv, acc.w * inv};
  reinterpret_cast<float4*>(neigh)[(size_t)wid * 64 + lane] = o;
}

// Fallback: f32 gather (if ws too small for xh copy).
__launch_bounds__(256)
__global__ void aggregate_f32_kernel(const float* __restrict__ x,
                                     const int* __restrict__ offsets,
                                     const int2* __restrict__ edges,
                                     float* __restrict__ neigh, int N) {
  int wid = blockIdx.x * 4 + (threadIdx.x >> 6);
  if (wid >= N) return;
  int lane = threadIdx.x & 63;
  int beg = offsets[wid];
  int end = offsets[wid + 1];
  const float4* x4 = reinterpret_cast<const float4*>(x);
  float4 acc = {0.f, 0.f, 0.f, 0.f};
  float ws = 0.f;
  int e = beg;
  for (; e + 1 < end; e += 2) {
    int2 e0 = edges[e], e1 = edges[e + 1];
    float w0 = __int_as_float(e0.y), w1 = __int_as_float(e1.y);
    float4 v0 = x4[(size_t)e0.x * 64 + lane];
    float4 v1 = x4[(size_t)e1.x * 64 + lane];
    acc.x += v0.x * w0 + v1.x * w1;
    acc.y += v0.y * w0 + v1.y * w1;
    acc.z += v0.z * w0 + v1.z * w1;
    acc.w += v0.w * w0 + v1.w * w1;
    ws += w0 + w1;
  }
  if (e < end) {
    int2 e0 = edges[e];
    float w0 = __int_as_float(e0.y);
    float4 v0 = x4[(size_t)e0.x * 64 + lane];
    acc.x += v0.x * w0;
    acc.y += v0.y * w0;
    acc.z += v0.z * w0;
    acc.w += v0.w * w0;
    ws += w0;
  }
  float inv = 1.f / fmaxf(ws, 1e-8f);
  float4 o = {acc.x * inv, acc.y * inv, acc.z * inv, acc.w * inv};
  reinterpret_cast<float4*>(neigh)[(size_t)wid * 64 + lane] = o;
}

// MFMA GEMM + L2-norm. 64 rows x 256 cols/block, 4 waves (wave w owns cols
// [w*64, w*64+64)). A staged in LDS fragment-major (lane-linear writes AND
// reads -> conflict-free); B fragments loaded per-wave directly from the
// L2-resident pre-staged weight layout (no B LDS). f16 hi/lo 3-pass split.
__launch_bounds__(256, 4)
__global__ void gemm_norm_kernel(const float* __restrict__ x,
                                 const float* __restrict__ neigh,
                                 const _Float16* __restrict__ Bhi,
                                 const _Float16* __restrict__ Blo,
                                 const float* __restrict__ bias,
                                 float* __restrict__ out, int N) {
  const int t = threadIdx.x;
  const int lane = t & 63;
  const int w = t >> 6;
  const int row0 = blockIdx.x * GR;

  // fragment-major: frag q = rt*64 + kseg*16 + (row&15); 8 halves each
  __shared__ _Float16 Ah[256 * 8];
  __shared__ _Float16 Al[256 * 8];
  __shared__ float ssb[GR][4];

  f32x4 acc[4][4];
#pragma unroll
  for (int rt = 0; rt < 4; ++rt)
#pragma unroll
    for (int ct = 0; ct < 4; ++ct) acc[rt][ct] = (f32x4){0.f, 0.f, 0.f, 0.f};

  // A-staging indices for this thread (frag q = t)
  const int st_rt = t >> 6;
  const int st_kseg = (t >> 4) & 3;
  const int st_r15 = t & 15;
  int st_row = row0 + st_rt * 16 + st_r15;
  if (st_row >= N) st_row = N - 1;

  for (int ks = 0; ks < 16; ++ks) {
    const int k0 = ks * GK;
    const float* __restrict__ A = (k0 < IN_F) ? x : neigh;
    const int kbase = (k0 & (IN_F - 1)) + st_kseg * 8;
    // --- stage A: 8 f32 -> 8 hi + 8 lo halves, frag-major LDS (lane-linear)
    {
      const float* src = A + (size_t)st_row * IN_F + kbase;
      float4 va = *reinterpret_cast<const float4*>(src);
      float4 vb = *reinterpret_cast<const float4*>(src + 4);
      _Float16 h0 = (_Float16)va.x, h1 = (_Float16)va.y, h2 = (_Float16)va.z,
               h3 = (_Float16)va.w, h4 = (_Float16)vb.x, h5 = (_Float16)vb.y,
               h6 = (_Float16)vb.z, h7 = (_Float16)vb.w;
      f16x8 hv = {h0, h1, h2, h3, h4, h5, h6, h7};
      f16x8 lv = {(_Float16)(va.x - (float)h0), (_Float16)(va.y - (float)h1),
                  (_Float16)(va.z - (float)h2), (_Float16)(va.w - (float)h3),
                  (_Float16)(vb.x - (float)h4), (_Float16)(vb.y - (float)h5),
                  (_Float16)(vb.z - (float)h6), (_Float16)(vb.w - (float)h7)};
      *reinterpret_cast<f16x8*>(&Ah[t * 8]) = hv;
      *reinterpret_cast<f16x8*>(&Al[t * 8]) = lv;
    }
    __syncthreads();
    // --- A fragments: lane-linear LDS reads (conflict-free)
    f16x8 aH[4], aL[4];
#pragma unroll
    for (int rt = 0; rt < 4; ++rt) {
      aH[rt] = *reinterpret_cast<const f16x8*>(&Ah[(rt * 64 + lane) * 8]);
      aL[rt] = *reinterpret_cast<const f16x8*>(&Al[(rt * 64 + lane) * 8]);
    }
    // --- B fragments straight from global (L2-hit) + MFMA
#pragma unroll
    for (int ct = 0; ct < 4; ++ct) {
      size_t boff = ((size_t)ks * 256 + (w * 64 + ct * 16 + (lane & 15))) * 32 +
                    (lane >> 4) * 8;
      f16x8 bH = *reinterpret_cast<const f16x8*>(Bhi + boff);
      f16x8 bL = *reinterpret_cast<const f16x8*>(Blo + boff);
#pragma unroll
      for (int rt = 0; rt < 4; ++rt) {
        acc[rt][ct] = __builtin_amdgcn_mfma_f32_16x16x32_f16(aH[rt], bH, acc[rt][ct], 0, 0, 0);
        acc[rt][ct] = __builtin_amdgcn_mfma_f32_16x16x32_f16(aH[rt], bL, acc[rt][ct], 0, 0, 0);
        acc[rt][ct] = __builtin_amdgcn_mfma_f32_16x16x32_f16(aL[rt], bH, acc[rt][ct], 0, 0, 0);
      }
    }
    __syncthreads();
  }

  float bv[4];
#pragma unroll
  for (int ct = 0; ct < 4; ++ct) bv[ct] = bias[w * 64 + ct * 16 + (lane & 15)];

#pragma unroll
  for (int rt = 0; rt < 4; ++rt)
#pragma unroll
    for (int i = 0; i < 4; ++i) {
      float ssv = 0.f;
#pragma unroll
      for (int ct = 0; ct < 4; ++ct) {
        float val = acc[rt][ct][i] + bv[ct];
        acc[rt][ct][i] = val;
        ssv += val * val;
      }
#pragma unroll
      for (int s = 1; s < 16; s <<= 1) ssv += __shfl_xor(ssv, s, 64);
      if ((lane & 15) == 0) ssb[rt * 16 + (lane >> 4) * 4 + i][w] = ssv;
    }
  __syncthreads();

#pragma unroll
  for (int rt = 0; rt < 4; ++rt)
#pragma unroll
    for (int i = 0; i < 4; ++i) {
      int rl = rt * 16 + (lane >> 4) * 4 + i;
      f32x4 s4 = *reinterpret_cast<const f32x4*>(&ssb[rl][0]);
      float ss = s4[0] + s4[1] + s4[2] + s4[3];
      int gr = row0 + rl;
      if (gr < N) {
        float scale = 1.0f / fmaxf(sqrtf(ss), 1e-12f);
#pragma unroll
        for (int ct = 0; ct < 4; ++ct)
          out[(size_t)gr * IN_F + w * 64 + ct * 16 + (lane & 15)] = acc[rt][ct][i] * scale;
      }
    }
}

extern "C" void kernel_launch(void* const* d_in, const int* in_sizes, int n_in,
                              void* d_out, int out_size, void* d_ws, size_t ws_size,
                              hipStream_t stream) {
  const float* x = (const float*)d_in[0];
  const int* ei = (const int*)d_in[1];
  const float* ew = (const float*)d_in[2];
  const float* Wself = (const float*)d_in[3];
  const float* Wneigh = (const float*)d_in[4];
  const float* bias = (const float*)d_in[5];
  float* out = (float*)d_out;

  const int N = in_sizes[0] / IN_F;
  const int E = in_sizes[2];

  // ws: neigh | Bhi | Blo | edges[int2] | counts | offsets | cursor | bsums |
  //     flag | xh (f16, only if ws allows)
  char* p = (char*)d_ws;
  float* neigh = (float*)p;                 p += (size_t)N * IN_F * 4;
  _Float16* Bhi = (_Float16*)p;             p += (size_t)K_TOT * IN_F * 2;
  _Float16* Blo = (_Float16*)p;             p += (size_t)K_TOT * IN_F * 2;
  int2* edges = (int2*)p;                   p += (size_t)E * 8;
  int* counts = (int*)p;                    p += (size_t)N * 4;
  int* offsets = (int*)p;                   p += (size_t)(N + 1) * 4;
  int* cursor = (int*)p;                    p += (size_t)N * 4;
  int* bsums = (int*)p;                     p += 128 * 4;
  int* flag = (int*)p;                      p += 16;  // keep 16B alignment
  _Float16* xh = (_Float16*)p;              p += (size_t)N * IN_F * 2;

  const bool use_f16 = ((size_t)(p - (char*)d_ws) <= ws_size);
  const int nb = (N + 1023) / 1024;

  hipMemsetAsync(counts, 0, (size_t)N * sizeof(int), stream);

  detect_i64_kernel<<<1, 256, 0, stream>>>(ei, flag);
  build_w_kernel<<<(K_TOT * IN_F) / 256, 256, 0, stream>>>(Wself, Wneigh, Bhi, Blo);
  if (use_f16) {
    int total8 = N * IN_F / 8;
    convert_x_kernel<<<(total8 + 255) / 256, 256, 0, stream>>>(x, xh, total8);
  }
  hist_kernel<<<(E + 255) / 256, 256, 0, stream>>>(ei, flag, counts, E);
  scan1_kernel<<<nb, 1024, 0, stream>>>(counts, offsets, bsums, N);
  scan2_kernel<<<1, 128, 0, stream>>>(bsums, nb);
  scan3_kernel<<<(N + 255) / 256, 256, 0, stream>>>(offsets, bsums, cursor, N, E);
  fill_kernel<<<(E + 255) / 256, 256, 0, stream>>>(ei, ew, flag, cursor, edges, E);
  if (use_f16) {
    aggregate_f16_kernel<<<(N + 3) / 4, 256, 0, stream>>>(xh, offsets, edges, neigh, N);
  } else {
    aggregate_f32_kernel<<<(N + 3) / 4, 256, 0, stream>>>(x, offsets, edges, neigh, N);
  }
  gemm_norm_kernel<<<(N + GR - 1) / GR, 256, 0, stream>>>(x, neigh, Bhi, Blo, bias, out, N);
}

// Round 8
// 381.403 us; speedup vs baseline: 15.0309x; 1.2878x over previous
//
#include <hip/hip_runtime.h>
#include <hip/hip_bf16.h>
#include <stdint.h>

#define IN_F 256
#define K_TOT 512
#define GR 64   // rows per gemm block

typedef __attribute__((ext_vector_type(8))) _Float16 f16x8;
typedef __attribute__((ext_vector_type(4))) _Float16 f16x4;
typedef __attribute__((ext_vector_type(4))) float f32x4;
typedef __attribute__((ext_vector_type(2))) float f32x2;

#if __has_builtin(__builtin_amdgcn_cvt_pk_f32_fp8) && __has_builtin(__builtin_amdgcn_cvt_pk_fp8_f32)
#define HW_FP8 1
#endif

// ---- fp8 e4m3 helpers (HW cvt with software RNE fallback) ----
__device__ __forceinline__ float fp8_dec1(uint32_t b) {
  // e4m3(bias7) -> f16(bias15): (b&0x7F)<<7 as f16, times 2^8 (exact, incl subnormals)
  union { uint16_t u; _Float16 h; } cv;
  cv.u = (uint16_t)((b & 0x7F) << 7);
  float v = (float)cv.h * 256.0f;
  return (b & 0x80) ? -v : v;
}
__device__ __forceinline__ uint32_t fp8_enc1(float f) {
  union { _Float16 h; uint16_t u; } cv;
  cv.h = (_Float16)(f * (1.0f / 256.0f));
  uint32_t s = (cv.u >> 8) & 0x80;
  uint32_t t = cv.u & 0x7FFF;
  uint32_t r = (t + 0x3F + ((t >> 7) & 1)) >> 7;  // RNE at 3-bit mantissa
  if (r > 0x7E) r = 0x7E;                          // clamp to 448
  return s | r;
}
__device__ __forceinline__ void fp8x4_dec(uint32_t w, float4& o) {
#ifdef HW_FP8
  f32x2 lo = __builtin_amdgcn_cvt_pk_f32_fp8((int)w, false);
  f32x2 hi = __builtin_amdgcn_cvt_pk_f32_fp8((int)w, true);
  o.x = lo[0]; o.y = lo[1]; o.z = hi[0]; o.w = hi[1];
#else
  o.x = fp8_dec1(w & 0xFF); o.y = fp8_dec1((w >> 8) & 0xFF);
  o.z = fp8_dec1((w >> 16) & 0xFF); o.w = fp8_dec1(w >> 24);
#endif
}
__device__ __forceinline__ uint32_t fp8x4_enc(float a, float b, float c, float d) {
#ifdef HW_FP8
  int r = __builtin_amdgcn_cvt_pk_fp8_f32(a, b, 0, false);
  r = __builtin_amdgcn_cvt_pk_fp8_f32(c, d, r, true);
  return (uint32_t)r;
#else
  return fp8_enc1(a) | (fp8_enc1(b) << 8) | (fp8_enc1(c) << 16) | (fp8_enc1(d) << 24);
#endif
}

// ---- fused init: build_w | x->fp8 convert | zero counts | detect i64 ----
// blocks [0,512): Bhi/Blo hi-lo split, layout B*[k/32][j][k%32]
// blocks [512,512+nconv): xq fp8 (4096 elems/block)
// blocks [.., +nmem): zero counts
// last block: int64-layout detection (odd words all zero over 2048 pairs)
__global__ void init_kernel(const float* __restrict__ x,
                            const float* __restrict__ Ws,
                            const float* __restrict__ Wn,
                            const int* __restrict__ ei,
                            _Float16* __restrict__ Bhi, _Float16* __restrict__ Blo,
                            uint32_t* __restrict__ xq, int* __restrict__ counts,
                            int* __restrict__ flag, int N, int nconv, int nmem) {
  __shared__ int bad_s[256];
  const int b = blockIdx.x;
  const int t = threadIdx.x;
  if (b < 512) {
    int idx = b * 256 + t;  // 0..131071
    int j = idx >> 9;
    int k = idx & 511;
    float v = (k < IN_F) ? Ws[j * IN_F + k] : Wn[j * IN_F + (k - IN_F)];
    _Float16 hi = (_Float16)v;
    _Float16 lo = (_Float16)(v - (float)hi);
    size_t addr = ((size_t)(k >> 5) * 256 + j) * 32 + (k & 31);
    Bhi[addr] = hi;
    Blo[addr] = lo;
  } else if (b < 512 + nconv) {
    size_t base = (size_t)(b - 512) * 4096 + (size_t)t * 16;
    size_t tot = (size_t)N * IN_F;
    if (base + 16 <= tot) {
      const float4* x4 = reinterpret_cast<const float4*>(x + base);
      uint4 o;
      float4 v0 = x4[0], v1 = x4[1], v2 = x4[2], v3 = x4[3];
      o.x = fp8x4_enc(v0.x, v0.y, v0.z, v0.w);
      o.y = fp8x4_enc(v1.x, v1.y, v1.z, v1.w);
      o.z = fp8x4_enc(v2.x, v2.y, v2.z, v2.w);
      o.w = fp8x4_enc(v3.x, v3.y, v3.z, v3.w);
      *reinterpret_cast<uint4*>(xq + base / 4) = o;
    }
  } else if (b < 512 + nconv + nmem) {
    int base = (b - 512 - nconv) * 1024 + t * 4;
#pragma unroll
    for (int j = 0; j < 4; ++j)
      if (base + j < N) counts[base + j] = 0;
  } else {
    int bad = 0;
#pragma unroll
    for (int p = 0; p < 8; ++p) {
      int i = t + p * 256;
      if (ei[2 * i + 1] != 0) bad = 1;
    }
    bad_s[t] = bad;
    __syncthreads();
    for (int s = 128; s > 0; s >>= 1) {
      if (t < s) bad_s[t] |= bad_s[t + s];
      __syncthreads();
    }
    if (t == 0) *flag = (bad_s[0] == 0) ? 1 : 0;
  }
}

__global__ void hist_kernel(const int* __restrict__ ei, const int* __restrict__ flag,
                            int* __restrict__ counts, int E) {
  int e = blockIdx.x * 256 + threadIdx.x;
  if (e >= E) return;
  int is64 = *flag;
  int dst = is64 ? ei[2 * (E + e)] : ei[E + e];
  atomicAdd(counts + dst, 1);
}

__global__ void scan1_kernel(const int* __restrict__ counts, int* __restrict__ offsets,
                             int* __restrict__ bsums, int N) {
  __shared__ int buf[1024];
  int t = threadIdx.x;
  int i = blockIdx.x * 1024 + t;
  int v = (i < N) ? counts[i] : 0;
  buf[t] = v;
  __syncthreads();
  for (int s = 1; s < 1024; s <<= 1) {
    int add = (t >= s) ? buf[t - s] : 0;
    __syncthreads();
    buf[t] += add;
    __syncthreads();
  }
  if (i < N) offsets[i] = buf[t] - v;
  if (t == 1023) bsums[blockIdx.x] = buf[1023];
}

// fused scan2+scan3: each block redundantly scans bsums (nb<=128) in LDS,
// then applies the block prefix, writing offsets and cursor.
__global__ void scan23_kernel(int* __restrict__ offsets, const int* __restrict__ bsums,
                              int* __restrict__ cursor, int N, int E, int nb) {
  __shared__ int sb[128];
  int t = threadIdx.x;
  int v = 0;
  if (t < 128) {
    v = (t < nb) ? bsums[t] : 0;
    sb[t] = v;
  }
  __syncthreads();
  for (int s = 1; s < 128; s <<= 1) {
    int add = 0;
    if (t < 128 && t >= s) add = sb[t - s];
    __syncthreads();
    if (t < 128) sb[t] += add;
    __syncthreads();
  }
  if (t < 128) sb[t] -= v;  // exclusive
  __syncthreads();
  int i = blockIdx.x * 256 + t;
  if (i < N) {
    int o = offsets[i] + sb[i >> 10];
    offsets[i] = o;
    cursor[i] = o;
  }
  if (i == 0) offsets[N] = E;
}

// CSR fill with packed (src, weight-bits) payload: one 8B random store.
__global__ void fill_kernel(const int* __restrict__ ei, const float* __restrict__ ew,
                            const int* __restrict__ flag, int* __restrict__ cursor,
                            int2* __restrict__ edges, int E) {
  int e = blockIdx.x * 256 + threadIdx.x;
  if (e >= E) return;
  int is64 = *flag;
  int src = is64 ? ei[2 * e] : ei[e];
  int dst = is64 ? ei[2 * (E + e)] : ei[E + e];
  int pos = atomicAdd(cursor + dst, 1);
  edges[pos] = make_int2(src, __float_as_int(ew[e]));
}

// One wave per dst node, fp8 gather (4B/lane = 256B/row), f32 accumulate,
// weighted-mean applied, f16 output row (feeds gemm A directly).
__launch_bounds__(256)
__global__ void aggregate_fp8_kernel(const uint32_t* __restrict__ xq,
                                     const int* __restrict__ offsets,
                                     const int2* __restrict__ edges,
                                     _Float16* __restrict__ neigh_h, int N) {
  int wid = blockIdx.x * 4 + (threadIdx.x >> 6);
  if (wid >= N) return;
  int lane = threadIdx.x & 63;
  int beg = offsets[wid];
  int end = offsets[wid + 1];
  float4 acc = {0.f, 0.f, 0.f, 0.f};
  float ws = 0.f;
  int e = beg;
  for (; e + 3 < end; e += 4) {
    int2 e0 = edges[e], e1 = edges[e + 1], e2 = edges[e + 2], e3 = edges[e + 3];
    float w0 = __int_as_float(e0.y), w1 = __int_as_float(e1.y);
    float w2 = __int_as_float(e2.y), w3 = __int_as_float(e3.y);
    uint32_t q0 = xq[(size_t)e0.x * 64 + lane];
    uint32_t q1 = xq[(size_t)e1.x * 64 + lane];
    uint32_t q2 = xq[(size_t)e2.x * 64 + lane];
    uint32_t q3 = xq[(size_t)e3.x * 64 + lane];
    float4 f0, f1, f2, f3;
    fp8x4_dec(q0, f0); fp8x4_dec(q1, f1); fp8x4_dec(q2, f2); fp8x4_dec(q3, f3);
    acc.x += f0.x * w0 + f1.x * w1 + f2.x * w2 + f3.x * w3;
    acc.y += f0.y * w0 + f1.y * w1 + f2.y * w2 + f3.y * w3;
    acc.z += f0.z * w0 + f1.z * w1 + f2.z * w2 + f3.z * w3;
    acc.w += f0.w * w0 + f1.w * w1 + f2.w * w2 + f3.w * w3;
    ws += w0 + w1 + w2 + w3;
  }
  for (; e < end; ++e) {
    int2 e0 = edges[e];
    float w0 = __int_as_float(e0.y);
    uint32_t q0 = xq[(size_t)e0.x * 64 + lane];
    float4 f0;
    fp8x4_dec(q0, f0);
    acc.x += f0.x * w0; acc.y += f0.y * w0; acc.z += f0.z * w0; acc.w += f0.w * w0;
    ws += w0;
  }
  float inv = 1.f / fmaxf(ws, 1e-8f);
  f16x4 o = {(_Float16)(acc.x * inv), (_Float16)(acc.y * inv),
             (_Float16)(acc.z * inv), (_Float16)(acc.w * inv)};
  *reinterpret_cast<f16x4*>(neigh_h + (size_t)wid * IN_F + lane * 4) = o;
}

// MFMA GEMM + L2-norm. 64 rows x 256 cols/block, 4 waves. A is pure f16
// (staged frag-major in LDS, lane-linear both ways); B hi/lo f16 fragments
// loaded straight from the L2-resident pre-staged layout. 2 MFMA passes:
// Ah*Bh + Ah*Bl.
__launch_bounds__(256, 4)
__global__ void gemm_norm_kernel(const float* __restrict__ x,
                                 const _Float16* __restrict__ neigh_h,
                                 const _Float16* __restrict__ Bhi,
                                 const _Float16* __restrict__ Blo,
                                 const float* __restrict__ bias,
                                 float* __restrict__ out, int N) {
  const int t = threadIdx.x;
  const int lane = t & 63;
  const int w = t >> 6;
  const int row0 = blockIdx.x * GR;

  __shared__ _Float16 Ah[256 * 8];  // frag-major: frag q=rt*64+kseg*16+r15
  __shared__ float ssb[GR][4];

  f32x4 acc[4][4];
#pragma unroll
  for (int rt = 0; rt < 4; ++rt)
#pragma unroll
    for (int ct = 0; ct < 4; ++ct) acc[rt][ct] = (f32x4){0.f, 0.f, 0.f, 0.f};

  const int st_kseg = (t >> 4) & 3;
  int st_row = row0 + (t >> 6) * 16 + (t & 15);
  if (st_row >= N) st_row = N - 1;

  for (int ks = 0; ks < 16; ++ks) {
    const int kbase = ((ks * 32) & (IN_F - 1)) + st_kseg * 8;
    // --- stage A fragment (8 f16) ---
    f16x8 hv;
    if (ks < 8) {
      const float* src = x + (size_t)st_row * IN_F + kbase;
      float4 va = *reinterpret_cast<const float4*>(src);
      float4 vb = *reinterpret_cast<const float4*>(src + 4);
      hv = (f16x8){(_Float16)va.x, (_Float16)va.y, (_Float16)va.z, (_Float16)va.w,
                   (_Float16)vb.x, (_Float16)vb.y, (_Float16)vb.z, (_Float16)vb.w};
    } else {
      hv = *reinterpret_cast<const f16x8*>(neigh_h + (size_t)st_row * IN_F + kbase);
    }
    *reinterpret_cast<f16x8*>(&Ah[t * 8]) = hv;
    __syncthreads();
    // --- A fragments: lane-linear LDS reads ---
    f16x8 aH[4];
#pragma unroll
    for (int rt = 0; rt < 4; ++rt)
      aH[rt] = *reinterpret_cast<const f16x8*>(&Ah[(rt * 64 + lane) * 8]);
    // --- B fragments from global (L2-hit) + MFMA ---
#pragma unroll
    for (int ct = 0; ct < 4; ++ct) {
      size_t boff = ((size_t)ks * 256 + (w * 64 + ct * 16 + (lane & 15))) * 32 +
                    (lane >> 4) * 8;
      f16x8 bH = *reinterpret_cast<const f16x8*>(Bhi + boff);
      f16x8 bL = *reinterpret_cast<const f16x8*>(Blo + boff);
#pragma unroll
      for (int rt = 0; rt < 4; ++rt) {
        acc[rt][ct] = __builtin_amdgcn_mfma_f32_16x16x32_f16(aH[rt], bH, acc[rt][ct], 0, 0, 0);
        acc[rt][ct] = __builtin_amdgcn_mfma_f32_16x16x32_f16(aH[rt], bL, acc[rt][ct], 0, 0, 0);
      }
    }
    __syncthreads();
  }

  float bv[4];
#pragma unroll
  for (int ct = 0; ct < 4; ++ct) bv[ct] = bias[w * 64 + ct * 16 + (lane & 15)];

#pragma unroll
  for (int rt = 0; rt < 4; ++rt)
#pragma unroll
    for (int i = 0; i < 4; ++i) {
      float ssv = 0.f;
#pragma unroll
      for (int ct = 0; ct < 4; ++ct) {
        float val = acc[rt][ct][i] + bv[ct];
        acc[rt][ct][i] = val;
        ssv += val * val;
      }
#pragma unroll
      for (int s = 1; s < 16; s <<= 1) ssv += __shfl_xor(ssv, s, 64);
      if ((lane & 15) == 0) ssb[rt * 16 + (lane >> 4) * 4 + i][w] = ssv;
    }
  __syncthreads();

#pragma unroll
  for (int rt = 0; rt < 4; ++rt)
#pragma unroll
    for (int i = 0; i < 4; ++i) {
      int rl = rt * 16 + (lane >> 4) * 4 + i;
      f32x4 s4 = *reinterpret_cast<const f32x4*>(&ssb[rl][0]);
      float ss = s4[0] + s4[1] + s4[2] + s4[3];
      int gr = row0 + rl;
      if (gr < N) {
        float scale = 1.0f / fmaxf(sqrtf(ss), 1e-12f);
#pragma unroll
        for (int ct = 0; ct < 4; ++ct)
          out[(size_t)gr * IN_F + w * 64 + ct * 16 + (lane & 15)] = acc[rt][ct][i] * scale;
      }
    }
}

extern "C" void kernel_launch(void* const* d_in, const int* in_sizes, int n_in,
                              void* d_out, int out_size, void* d_ws, size_t ws_size,
                              hipStream_t stream) {
  const float* x = (const float*)d_in[0];
  const int* ei = (const int*)d_in[1];
  const float* ew = (const float*)d_in[2];
  const float* Wself = (const float*)d_in[3];
  const float* Wneigh = (const float*)d_in[4];
  const float* bias = (const float*)d_in[5];
  float* out = (float*)d_out;

  const int N = in_sizes[0] / IN_F;
  const int E = in_sizes[2];

  // ws: neigh_h[N*256 f16] | Bhi | Blo | xq[N*64 u32] | edges[E int2] |
  //     counts[N] | offsets[N+1] | cursor[N] | bsums[128] | flag
  char* p = (char*)d_ws;
  _Float16* neigh_h = (_Float16*)p;  p += (size_t)N * IN_F * 2;
  _Float16* Bhi = (_Float16*)p;      p += (size_t)K_TOT * IN_F * 2;
  _Float16* Blo = (_Float16*)p;      p += (size_t)K_TOT * IN_F * 2;
  uint32_t* xq = (uint32_t*)p;       p += (size_t)N * IN_F;
  int2* edges = (int2*)p;            p += (size_t)E * 8;
  int* counts = (int*)p;             p += (size_t)N * 4;
  int* offsets = (int*)p;            p += (size_t)(N + 1) * 4;
  int* cursor = (int*)p;             p += (size_t)N * 4;
  int* bsums = (int*)p;              p += 128 * 4;
  int* flag = (int*)p;

  const int nconv = (int)(((size_t)N * IN_F + 4095) / 4096);
  const int nmem = (N + 1023) / 1024;
  const int nb = (N + 1023) / 1024;

  init_kernel<<<512 + nconv + nmem + 1, 256, 0, stream>>>(
      x, Wself, Wneigh, ei, Bhi, Blo, xq, counts, flag, N, nconv, nmem);
  hist_kernel<<<(E + 255) / 256, 256, 0, stream>>>(ei, flag, counts, E);
  scan1_kernel<<<nb, 1024, 0, stream>>>(counts, offsets, bsums, N);
  scan23_kernel<<<(N + 255) / 256, 256, 0, stream>>>(offsets, bsums, cursor, N, E, nb);
  fill_kernel<<<(E + 255) / 256, 256, 0, stream>>>(ei, ew, flag, cursor, edges, E);
  aggregate_fp8_kernel<<<(N + 3) / 4, 256, 0, stream>>>(xq, offsets, edges, neigh_h, N);
  gemm_norm_kernel<<<(N + GR - 1) / GR, 256, 0, stream>>>(x, neigh_h, Bhi, Blo, bias,
                                                          out, N);
}

// Round 9
// 332.141 us; speedup vs baseline: 17.2602x; 1.1483x over previous
//
#include <hip/hip_runtime.h>
#include <hip/hip_bf16.h>
#include <stdint.h>

#define IN_F 256
#define K_TOT 512
#define GR 64   // rows per gemm block

typedef __attribute__((ext_vector_type(8))) _Float16 f16x8;
typedef __attribute__((ext_vector_type(4))) _Float16 f16x4;
typedef __attribute__((ext_vector_type(4))) float f32x4;
typedef __attribute__((ext_vector_type(2))) float f32x2;

#if __has_builtin(__builtin_amdgcn_cvt_pk_f32_fp8) && __has_builtin(__builtin_amdgcn_cvt_pk_fp8_f32)
#define HW_FP8 1
#endif

// ---- fp8 e4m3 helpers (HW cvt with software RNE fallback) ----
__device__ __forceinline__ float fp8_dec1(uint32_t b) {
  union { uint16_t u; _Float16 h; } cv;
  cv.u = (uint16_t)((b & 0x7F) << 7);
  float v = (float)cv.h * 256.0f;
  return (b & 0x80) ? -v : v;
}
__device__ __forceinline__ uint32_t fp8_enc1(float f) {
  union { _Float16 h; uint16_t u; } cv;
  cv.h = (_Float16)(f * (1.0f / 256.0f));
  uint32_t s = (cv.u >> 8) & 0x80;
  uint32_t t = cv.u & 0x7FFF;
  uint32_t r = (t + 0x3F + ((t >> 7) & 1)) >> 7;  // RNE at 3-bit mantissa
  if (r > 0x7E) r = 0x7E;                          // clamp to 448
  return s | r;
}
__device__ __forceinline__ void fp8x4_dec(uint32_t w, float4& o) {
#ifdef HW_FP8
  f32x2 lo = __builtin_amdgcn_cvt_pk_f32_fp8((int)w, false);
  f32x2 hi = __builtin_amdgcn_cvt_pk_f32_fp8((int)w, true);
  o.x = lo[0]; o.y = lo[1]; o.z = hi[0]; o.w = hi[1];
#else
  o.x = fp8_dec1(w & 0xFF); o.y = fp8_dec1((w >> 8) & 0xFF);
  o.z = fp8_dec1((w >> 16) & 0xFF); o.w = fp8_dec1(w >> 24);
#endif
}
__device__ __forceinline__ uint32_t fp8x4_enc(float a, float b, float c, float d) {
#ifdef HW_FP8
  int r = __builtin_amdgcn_cvt_pk_fp8_f32(a, b, 0, false);
  r = __builtin_amdgcn_cvt_pk_fp8_f32(c, d, r, true);
  return (uint32_t)r;
#else
  return fp8_enc1(a) | (fp8_enc1(b) << 8) | (fp8_enc1(c) << 16) | (fp8_enc1(d) << 24);
#endif
}

// ---- fused init: build_w | x->fp8 convert | zero counts | detect i64 ----
__global__ void init_kernel(const float* __restrict__ x,
                            const float* __restrict__ Ws,
                            const float* __restrict__ Wn,
                            const int* __restrict__ ei,
                            _Float16* __restrict__ Bhi, _Float16* __restrict__ Blo,
                            uint32_t* __restrict__ xq, int* __restrict__ counts,
                            int* __restrict__ flag, int N, int nconv, int nmem) {
  __shared__ int bad_s[256];
  const int b = blockIdx.x;
  const int t = threadIdx.x;
  if (b < 512) {
    int idx = b * 256 + t;  // 0..131071
    int j = idx >> 9;
    int k = idx & 511;
    float v = (k < IN_F) ? Ws[j * IN_F + k] : Wn[j * IN_F + (k - IN_F)];
    _Float16 hi = (_Float16)v;
    _Float16 lo = (_Float16)(v - (float)hi);
    size_t addr = ((size_t)(k >> 5) * 256 + j) * 32 + (k & 31);
    Bhi[addr] = hi;
    Blo[addr] = lo;
  } else if (b < 512 + nconv) {
    size_t base = (size_t)(b - 512) * 4096 + (size_t)t * 16;
    size_t tot = (size_t)N * IN_F;
    if (base + 16 <= tot) {
      const float4* x4 = reinterpret_cast<const float4*>(x + base);
      uint4 o;
      float4 v0 = x4[0], v1 = x4[1], v2 = x4[2], v3 = x4[3];
      o.x = fp8x4_enc(v0.x, v0.y, v0.z, v0.w);
      o.y = fp8x4_enc(v1.x, v1.y, v1.z, v1.w);
      o.z = fp8x4_enc(v2.x, v2.y, v2.z, v2.w);
      o.w = fp8x4_enc(v3.x, v3.y, v3.z, v3.w);
      *reinterpret_cast<uint4*>(xq + base / 4) = o;
    }
  } else if (b < 512 + nconv + nmem) {
    int base = (b - 512 - nconv) * 1024 + t * 4;
#pragma unroll
    for (int j = 0; j < 4; ++j)
      if (base + j < N) counts[base + j] = 0;
  } else {
    int bad = 0;
#pragma unroll
    for (int p = 0; p < 8; ++p) {
      int i = t + p * 256;
      if (ei[2 * i + 1] != 0) bad = 1;
    }
    bad_s[t] = bad;
    __syncthreads();
    for (int s = 128; s > 0; s >>= 1) {
      if (t < s) bad_s[t] |= bad_s[t + s];
      __syncthreads();
    }
    if (t == 0) *flag = (bad_s[0] == 0) ? 1 : 0;
  }
}

__global__ void hist_kernel(const int* __restrict__ ei, const int* __restrict__ flag,
                            int* __restrict__ counts, int E) {
  int e = blockIdx.x * 256 + threadIdx.x;
  if (e >= E) return;
  int is64 = *flag;
  int dst = is64 ? ei[2 * (E + e)] : ei[E + e];
  atomicAdd(counts + dst, 1);
}

__global__ void scan1_kernel(const int* __restrict__ counts, int* __restrict__ offsets,
                             int* __restrict__ bsums, int N) {
  __shared__ int buf[1024];
  int t = threadIdx.x;
  int i = blockIdx.x * 1024 + t;
  int v = (i < N) ? counts[i] : 0;
  buf[t] = v;
  __syncthreads();
  for (int s = 1; s < 1024; s <<= 1) {
    int add = (t >= s) ? buf[t - s] : 0;
    __syncthreads();
    buf[t] += add;
    __syncthreads();
  }
  if (i < N) offsets[i] = buf[t] - v;
  if (t == 1023) bsums[blockIdx.x] = buf[1023];
}

// fused scan2+scan3: each block redundantly scans bsums (nb<=128) in LDS.
__global__ void scan23_kernel(int* __restrict__ offsets, const int* __restrict__ bsums,
                              int* __restrict__ cursor, int N, int E, int nb) {
  __shared__ int sb[128];
  int t = threadIdx.x;
  int v = 0;
  if (t < 128) {
    v = (t < nb) ? bsums[t] : 0;
    sb[t] = v;
  }
  __syncthreads();
  for (int s = 1; s < 128; s <<= 1) {
    int add = 0;
    if (t < 128 && t >= s) add = sb[t - s];
    __syncthreads();
    if (t < 128) sb[t] += add;
    __syncthreads();
  }
  if (t < 128) sb[t] -= v;  // exclusive
  __syncthreads();
  int i = blockIdx.x * 256 + t;
  if (i < N) {
    int o = offsets[i] + sb[i >> 10];
    offsets[i] = o;
    cursor[i] = o;
  }
  if (i == 0) offsets[N] = E;
}

// XCD-bucketed CSR fill, 4B packed entries (src<<15 | w15).
// bid%8 = bucket q (round-robin blockIdx->XCD): block only handles edges with
// dst in bucket q's node range -> its stores hit a ~1.6MB CSR window that is
// resident in XCD q's own L2 -> full-line accumulation before writeback.
// Consecutive bids share the edge chunk -> ei/ew read from HBM once, L3 after.
__global__ void fill_kernel(const int* __restrict__ ei, const float* __restrict__ ew,
                            const int* __restrict__ flag, int* __restrict__ cursor,
                            uint32_t* __restrict__ edges, int E, int nper) {
  int q = blockIdx.x & 7;
  int e = (blockIdx.x >> 3) * 256 + threadIdx.x;
  if (e >= E) return;
  int is64 = *flag;
  int dst = is64 ? ei[2 * (E + e)] : ei[E + e];
  if (dst / nper != q) return;
  int src = is64 ? ei[2 * e] : ei[e];
  uint32_t w15 = (uint32_t)__float2int_rn(ew[e] * 32767.0f);
  int pos = atomicAdd(cursor + dst, 1);
  edges[pos] = ((uint32_t)src << 15) | w15;
}

// One wave per dst node, fp8 gather (4B/lane = 256B/row), f32 accumulate,
// weighted-mean applied, f16 output row (feeds gemm A directly).
__launch_bounds__(256)
__global__ void aggregate_fp8_kernel(const uint32_t* __restrict__ xq,
                                     const int* __restrict__ offsets,
                                     const uint32_t* __restrict__ edges,
                                     _Float16* __restrict__ neigh_h, int N) {
  int wid = blockIdx.x * 4 + (threadIdx.x >> 6);
  if (wid >= N) return;
  int lane = threadIdx.x & 63;
  int beg = offsets[wid];
  int end = offsets[wid + 1];
  float4 acc = {0.f, 0.f, 0.f, 0.f};
  float ws = 0.f;
  const float wscale = 1.0f / 32767.0f;
  int e = beg;
  for (; e + 3 < end; e += 4) {
    uint32_t n0 = edges[e], n1 = edges[e + 1], n2 = edges[e + 2], n3 = edges[e + 3];
    float w0 = (float)(n0 & 0x7FFF) * wscale, w1 = (float)(n1 & 0x7FFF) * wscale;
    float w2 = (float)(n2 & 0x7FFF) * wscale, w3 = (float)(n3 & 0x7FFF) * wscale;
    uint32_t q0 = xq[(size_t)(n0 >> 15) * 64 + lane];
    uint32_t q1 = xq[(size_t)(n1 >> 15) * 64 + lane];
    uint32_t q2 = xq[(size_t)(n2 >> 15) * 64 + lane];
    uint32_t q3 = xq[(size_t)(n3 >> 15) * 64 + lane];
    float4 f0, f1, f2, f3;
    fp8x4_dec(q0, f0); fp8x4_dec(q1, f1); fp8x4_dec(q2, f2); fp8x4_dec(q3, f3);
    acc.x += f0.x * w0 + f1.x * w1 + f2.x * w2 + f3.x * w3;
    acc.y += f0.y * w0 + f1.y * w1 + f2.y * w2 + f3.y * w3;
    acc.z += f0.z * w0 + f1.z * w1 + f2.z * w2 + f3.z * w3;
    acc.w += f0.w * w0 + f1.w * w1 + f2.w * w2 + f3.w * w3;
    ws += w0 + w1 + w2 + w3;
  }
  for (; e < end; ++e) {
    uint32_t n0 = edges[e];
    float w0 = (float)(n0 & 0x7FFF) * wscale;
    uint32_t q0 = xq[(size_t)(n0 >> 15) * 64 + lane];
    float4 f0;
    fp8x4_dec(q0, f0);
    acc.x += f0.x * w0; acc.y += f0.y * w0; acc.z += f0.z * w0; acc.w += f0.w * w0;
    ws += w0;
  }
  float inv = 1.f / fmaxf(ws, 1e-8f);
  f16x4 o = {(_Float16)(acc.x * inv), (_Float16)(acc.y * inv),
             (_Float16)(acc.z * inv), (_Float16)(acc.w * inv)};
  *reinterpret_cast<f16x4*>(neigh_h + (size_t)wid * IN_F + lane * 4) = o;
}

// MFMA GEMM + L2-norm (round-8 structure: frag-major LDS A, global-L2 B).
__launch_bounds__(256, 4)
__global__ void gemm_norm_kernel(const float* __restrict__ x,
                                 const _Float16* __restrict__ neigh_h,
                                 const _Float16* __restrict__ Bhi,
                                 const _Float16* __restrict__ Blo,
                                 const float* __restrict__ bias,
                                 float* __restrict__ out, int N) {
  const int t = threadIdx.x;
  const int lane = t & 63;
  const int w = t >> 6;
  const int row0 = blockIdx.x * GR;

  __shared__ _Float16 Ah[256 * 8];  // frag-major: frag q=rt*64+kseg*16+r15
  __shared__ float ssb[GR][4];

  f32x4 acc[4][4];
#pragma unroll
  for (int rt = 0; rt < 4; ++rt)
#pragma unroll
    for (int ct = 0; ct < 4; ++ct) acc[rt][ct] = (f32x4){0.f, 0.f, 0.f, 0.f};

  const int st_kseg = (t >> 4) & 3;
  int st_row = row0 + (t >> 6) * 16 + (t & 15);
  if (st_row >= N) st_row = N - 1;

  for (int ks = 0; ks < 16; ++ks) {
    const int kbase = ((ks * 32) & (IN_F - 1)) + st_kseg * 8;
    f16x8 hv;
    if (ks < 8) {
      const float* src = x + (size_t)st_row * IN_F + kbase;
      float4 va = *reinterpret_cast<const float4*>(src);
      float4 vb = *reinterpret_cast<const float4*>(src + 4);
      hv = (f16x8){(_Float16)va.x, (_Float16)va.y, (_Float16)va.z, (_Float16)va.w,
                   (_Float16)vb.x, (_Float16)vb.y, (_Float16)vb.z, (_Float16)vb.w};
    } else {
      hv = *reinterpret_cast<const f16x8*>(neigh_h + (size_t)st_row * IN_F + kbase);
    }
    *reinterpret_cast<f16x8*>(&Ah[t * 8]) = hv;
    __syncthreads();
    f16x8 aH[4];
#pragma unroll
    for (int rt = 0; rt < 4; ++rt)
      aH[rt] = *reinterpret_cast<const f16x8*>(&Ah[(rt * 64 + lane) * 8]);
#pragma unroll
    for (int ct = 0; ct < 4; ++ct) {
      size_t boff = ((size_t)ks * 256 + (w * 64 + ct * 16 + (lane & 15))) * 32 +
                    (lane >> 4) * 8;
      f16x8 bH = *reinterpret_cast<const f16x8*>(Bhi + boff);
      f16x8 bL = *reinterpret_cast<const f16x8*>(Blo + boff);
#pragma unroll
      for (int rt = 0; rt < 4; ++rt) {
        acc[rt][ct] = __builtin_amdgcn_mfma_f32_16x16x32_f16(aH[rt], bH, acc[rt][ct], 0, 0, 0);
        acc[rt][ct] = __builtin_amdgcn_mfma_f32_16x16x32_f16(aH[rt], bL, acc[rt][ct], 0, 0, 0);
      }
    }
    __syncthreads();
  }

  float bv[4];
#pragma unroll
  for (int ct = 0; ct < 4; ++ct) bv[ct] = bias[w * 64 + ct * 16 + (lane & 15)];

#pragma unroll
  for (int rt = 0; rt < 4; ++rt)
#pragma unroll
    for (int i = 0; i < 4; ++i) {
      float ssv = 0.f;
#pragma unroll
      for (int ct = 0; ct < 4; ++ct) {
        float val = acc[rt][ct][i] + bv[ct];
        acc[rt][ct][i] = val;
        ssv += val * val;
      }
#pragma unroll
      for (int s = 1; s < 16; s <<= 1) ssv += __shfl_xor(ssv, s, 64);
      if ((lane & 15) == 0) ssb[rt * 16 + (lane >> 4) * 4 + i][w] = ssv;
    }
  __syncthreads();

#pragma unroll
  for (int rt = 0; rt < 4; ++rt)
#pragma unroll
    for (int i = 0; i < 4; ++i) {
      int rl = rt * 16 + (lane >> 4) * 4 + i;
      f32x4 s4 = *reinterpret_cast<const f32x4*>(&ssb[rl][0]);
      float ss = s4[0] + s4[1] + s4[2] + s4[3];
      int gr = row0 + rl;
      if (gr < N) {
        float scale = 1.0f / fmaxf(sqrtf(ss), 1e-12f);
#pragma unroll
        for (int ct = 0; ct < 4; ++ct)
          out[(size_t)gr * IN_F + w * 64 + ct * 16 + (lane & 15)] = acc[rt][ct][i] * scale;
      }
    }
}

extern "C" void kernel_launch(void* const* d_in, const int* in_sizes, int n_in,
                              void* d_out, int out_size, void* d_ws, size_t ws_size,
                              hipStream_t stream) {
  const float* x = (const float*)d_in[0];
  const int* ei = (const int*)d_in[1];
  const float* ew = (const float*)d_in[2];
  const float* Wself = (const float*)d_in[3];
  const float* Wneigh = (const float*)d_in[4];
  const float* bias = (const float*)d_in[5];
  float* out = (float*)d_out;

  const int N = in_sizes[0] / IN_F;
  const int E = in_sizes[2];

  // ws: neigh_h[N*256 f16] | Bhi | Blo | xq[N*64 u32] | edges[E u32] |
  //     counts[N] | offsets[N+1] | cursor[N] | bsums[128] | flag
  char* p = (char*)d_ws;
  _Float16* neigh_h = (_Float16*)p;  p += (size_t)N * IN_F * 2;
  _Float16* Bhi = (_Float16*)p;      p += (size_t)K_TOT * IN_F * 2;
  _Float16* Blo = (_Float16*)p;      p += (size_t)K_TOT * IN_F * 2;
  uint32_t* xq = (uint32_t*)p;       p += (size_t)N * IN_F;
  uint32_t* edges = (uint32_t*)p;    p += (size_t)E * 4;
  int* counts = (int*)p;             p += (size_t)N * 4;
  int* offsets = (int*)p;            p += (size_t)(N + 1) * 4;
  int* cursor = (int*)p;             p += (size_t)N * 4;
  int* bsums = (int*)p;              p += 128 * 4;
  int* flag = (int*)p;

  const int nconv = (int)(((size_t)N * IN_F + 4095) / 4096);
  const int nmem = (N + 1023) / 1024;
  const int nb = (N + 1023) / 1024;
  const int nper = (N + 7) / 8;  // nodes per XCD bucket

  init_kernel<<<512 + nconv + nmem + 1, 256, 0, stream>>>(
      x, Wself, Wneigh, ei, Bhi, Blo, xq, counts, flag, N, nconv, nmem);
  hist_kernel<<<(E + 255) / 256, 256, 0, stream>>>(ei, flag, counts, E);
  scan1_kernel<<<nb, 1024, 0, stream>>>(counts, offsets, bsums, N);
  scan23_kernel<<<(N + 255) / 256, 256, 0, stream>>>(offsets, bsums, cursor, N, E, nb);
  fill_kernel<<<((E + 255) / 256) * 8, 256, 0, stream>>>(ei, ew, flag, cursor, edges,
                                                         E, nper);
  aggregate_fp8_kernel<<<(N + 3) / 4, 256, 0, stream>>>(xq, offsets, edges, neigh_h, N);
  gemm_norm_kernel<<<(N + GR - 1) / GR, 256, 0, stream>>>(x, neigh_h, Bhi, Blo, bias,
                                                          out, N);
}